// Round 8
// baseline (439.379 us; speedup 1.0000x reference)
//
#include <hip/hip_runtime.h>
#include <hip/hip_fp16.h>

#define NN 100000
#define NE 1600000
#define W_BKT 128
#define NB_BKT ((NN + W_BKT - 1) / W_BKT)   // 782
#define TILE_E 16384                         // edges per counting-sort tile
#define NT ((NE + TILE_E - 1) / TILE_E)      // 98
#define STAGE_CAP 4352                       // LDS staging (avg bucket ~2048)
// IN=128, HID=64, OUT=32

typedef _Float16 half2v __attribute__((ext_vector_type(2)));
typedef _Float16 half4v __attribute__((ext_vector_type(4)));
typedef _Float16 half8v __attribute__((ext_vector_type(8)));
typedef float float2v __attribute__((ext_vector_type(2)));
typedef float float4v __attribute__((ext_vector_type(4)));

// ---- deterministic two-pass bucket sort + fused CSR/deg build (NO global atomics) ----

__global__ __launch_bounds__(256) void k_cnt(const int* __restrict__ dst,
                                             int* __restrict__ counts) {
    __shared__ int hc[NB_BKT];
    int tid = threadIdx.x;
    for (int i = tid; i < NB_BKT; i += 256) hc[i] = 0;
    __syncthreads();
    int base = blockIdx.x * TILE_E;
    int lim = base + TILE_E; if (lim > NE) lim = NE;
    for (int e = base + tid; e < lim; e += 256)
        atomicAdd(&hc[dst[e] >> 7], 1);
    __syncthreads();
    for (int i = tid; i < NB_BKT; i += 256)
        counts[blockIdx.x * NB_BKT + i] = hc[i];
}

// scan bucket totals -> bucket_base, AND convert counts to per-tile offsets
__global__ __launch_bounds__(1024) void k_bscan(int* __restrict__ counts,
                                                int* __restrict__ bucket_base) {
    __shared__ int buf[1024];
    int tid = threadIdx.x;
    int total = 0;
    if (tid < NB_BKT)
        for (int t = 0; t < NT; ++t) total += counts[t * NB_BKT + tid];
    buf[tid] = total;
    __syncthreads();
    for (int off = 1; off < 1024; off <<= 1) {
        int v = (tid >= off) ? buf[tid - off] : 0;
        __syncthreads();
        buf[tid] += v;
        __syncthreads();
    }
    if (tid < NB_BKT) {
        int off = buf[tid] - total;              // exclusive prefix
        bucket_base[tid] = off;
        for (int t = 0; t < NT; ++t) {
            int c = counts[t * NB_BKT + tid];
            counts[t * NB_BKT + tid] = off;
            off += c;
        }
    }
    if (tid == 0) bucket_base[NB_BKT] = NE;
}

// place edges into dst-bucket order; record original edge id (bucket order, used by decode)
__global__ __launch_bounds__(256) void k_place(const int* __restrict__ src,
                                               const int* __restrict__ dst,
                                               const int* __restrict__ counts,
                                               int* __restrict__ ebuf,
                                               int* __restrict__ eid) {
    __shared__ int cur[NB_BKT];
    int tid = threadIdx.x;
    for (int i = tid; i < NB_BKT; i += 256)
        cur[i] = counts[blockIdx.x * NB_BKT + i];
    __syncthreads();
    int base = blockIdx.x * TILE_E;
    int lim = base + TILE_E; if (lim > NE) lim = NE;
    for (int e = base + tid; e < lim; e += 256) {
        int s = src[e], d = dst[e];
        int pos = atomicAdd(&cur[d >> 7], 1);     // LDS atomic
        ebuf[pos] = (s << 7) | (d & 127);
        eid[pos] = e;
    }
}

// one block per bucket: LDS-stage the bucket's ebuf slice, count 128 node degs,
// prefix-scan -> row_ptr + dis, then scatter to csr_src. (ebuf/eid stay intact.)
__global__ __launch_bounds__(256) void k_build(const int* __restrict__ bucket_base,
                                               const int* __restrict__ ebuf,
                                               int* __restrict__ csr_src,
                                               int* __restrict__ row_ptr,
                                               float* __restrict__ dis) {
    __shared__ int deg[W_BKT];
    __shared__ int pre[W_BKT];
    __shared__ int cur[W_BKT];
    __shared__ int stage[STAGE_CAP];
    int b = blockIdx.x;
    int tid = threadIdx.x;
    int beg = bucket_base[b], end = bucket_base[b + 1];
    int n = end - beg;
    if (tid < W_BKT) deg[tid] = 0;
    __syncthreads();
    bool fits = (n <= STAGE_CAP);
    if (fits) {
        for (int i = tid; i < n; i += 256) {
            int val = ebuf[beg + i];
            stage[i] = val;
            atomicAdd(&deg[val & 127], 1);
        }
    } else {
        for (int i = tid; i < n; i += 256)
            atomicAdd(&deg[ebuf[beg + i] & 127], 1);
    }
    __syncthreads();
    if (tid < W_BKT) pre[tid] = deg[tid];
    __syncthreads();
    for (int off = 1; off < W_BKT; off <<= 1) {
        int v = (tid >= off && tid < W_BKT) ? pre[tid - off] : 0;
        __syncthreads();
        if (tid < W_BKT) pre[tid] += v;
        __syncthreads();
    }
    if (tid < W_BKT) {
        int v = b * W_BKT + tid;
        int rp = beg + pre[tid] - deg[tid];      // exclusive prefix
        if (v < NN) {
            row_ptr[v] = rp;
            dis[v] = rsqrtf((float)(1 + deg[tid]));
        }
        cur[tid] = rp;
    }
    if (b == NB_BKT - 1 && tid == 0) row_ptr[NN] = NE;
    __syncthreads();
    if (fits) {
        for (int i = tid; i < n; i += 256) {
            int val = stage[i];
            int pos = atomicAdd(&cur[val & 127], 1);
            csr_src[pos] = val >> 7;
        }
    } else {
        for (int i = tid; i < n; i += 256) {
            int val = ebuf[beg + i];
            int pos = atomicAdd(&cur[val & 127], 1);
            csr_src[pos] = val >> 7;
        }
    }
}

// ---------------- dense transforms via MFMA (dis folded into stored rows) ----------------
// W pre-packed into fragment-ordered f16 hi/lo tables. GEMM1: Ah*Bh+Al*Bh+Ah*Bl
// (fp32-equivalent). GEMM2 input h is fp16 (exact) -> Ah*Bh+Ah*Bl only.

__global__ __launch_bounds__(256) void k_wprep(const float* __restrict__ W1,
                                               const float* __restrict__ Wmu,
                                               const float* __restrict__ Wls,
                                               _Float16* __restrict__ wf1h,
                                               _Float16* __restrict__ wf1l,
                                               _Float16* __restrict__ wf2h,
                                               _Float16* __restrict__ wf2l) {
    int tid = threadIdx.x;
    for (int f = tid; f < 4 * 4 * 64; f += 256) {
        int lane = f & 63;
        int kc = (f >> 6) & 3;
        int ct = f >> 8;
        int col = ct * 16 + (lane & 15);
        int k0 = kc * 32 + (lane >> 4) * 8;
#pragma unroll
        for (int j = 0; j < 8; ++j) {
            float w = W1[(k0 + j) * 64 + col];
            _Float16 hi = (_Float16)w;
            wf1h[f * 8 + j] = hi;
            wf1l[f * 8 + j] = (_Float16)(w - (float)hi);
        }
    }
    for (int f = tid; f < 4 * 2 * 64; f += 256) {
        int lane = f & 63;
        int kc = (f >> 6) & 1;
        int ct = f >> 7;
        int col = ct * 16 + (lane & 15);
        int k0 = kc * 32 + (lane >> 4) * 8;
#pragma unroll
        for (int j = 0; j < 8; ++j) {
            int k = k0 + j;
            float w = (col < 32) ? Wmu[k * 32 + col] : Wls[k * 32 + (col - 32)];
            _Float16 hi = (_Float16)w;
            wf2h[f * 8 + j] = hi;
            wf2l[f * 8 + j] = (_Float16)(w - (float)hi);
        }
    }
}

__device__ __forceinline__ void split8(const float4 a, const float4 b,
                                       half8v& hi, half8v& lo) {
    float v[8] = {a.x, a.y, a.z, a.w, b.x, b.y, b.z, b.w};
#pragma unroll
    for (int i = 0; i < 8; ++i) {
        _Float16 h = (_Float16)v[i];
        hi[i] = h;
        lo[i] = (_Float16)(v[i] - (float)h);
    }
}

// t1'[v] = dis[v] * (x[v] @ W1), stored fp16. 64 rows/block, 16 rows/wave, no LDS.
__global__ __launch_bounds__(256) void k_gemm1(const float* __restrict__ x,
                                               const _Float16* __restrict__ wf1h,
                                               const _Float16* __restrict__ wf1l,
                                               const float* __restrict__ dis,
                                               _Float16* __restrict__ t1) {
    int tid = threadIdx.x;
    int lane = tid & 63;
    int wv = tid >> 6;
    int wrow = blockIdx.x * 64 + wv * 16;
    int cl = lane & 15, kg = lane >> 4;
    const half8v* Bh = (const half8v*)wf1h;
    const half8v* Bl = (const half8v*)wf1l;
    float4v acc[4] = {};
    int r = wrow + cl;
    long rr = (r < NN) ? r : (NN - 1);
    const float4* xp = (const float4*)(x + rr * 128);
#pragma unroll
    for (int kc = 0; kc < 4; ++kc) {
        float4 xa = xp[kc * 8 + kg * 2];
        float4 xb = xp[kc * 8 + kg * 2 + 1];
        half8v ah, al;
        split8(xa, xb, ah, al);
#pragma unroll
        for (int ct = 0; ct < 4; ++ct) {
            half8v bh = Bh[(ct * 4 + kc) * 64 + lane];
            half8v bl = Bl[(ct * 4 + kc) * 64 + lane];
            acc[ct] = __builtin_amdgcn_mfma_f32_16x16x32_f16(ah, bh, acc[ct], 0, 0, 0);
            acc[ct] = __builtin_amdgcn_mfma_f32_16x16x32_f16(al, bh, acc[ct], 0, 0, 0);
            acc[ct] = __builtin_amdgcn_mfma_f32_16x16x32_f16(ah, bl, acc[ct], 0, 0, 0);
        }
    }
#pragma unroll
    for (int j = 0; j < 4; ++j) {
        int row = wrow + kg * 4 + j;
        if (row < NN) {
            float dv = dis[row];
#pragma unroll
            for (int ct = 0; ct < 4; ++ct)
                t1[(long)row * 64 + ct * 16 + cl] = (_Float16)(acc[ct][j] * dv);
        }
    }
}

// t2'[v] = dis[v] * (h[v] @ [Wmu | Wls]), h fp16 input, stored fp16
__global__ __launch_bounds__(256) void k_gemm2(const _Float16* __restrict__ h,
                                               const _Float16* __restrict__ wf2h,
                                               const _Float16* __restrict__ wf2l,
                                               const float* __restrict__ dis,
                                               _Float16* __restrict__ t2) {
    int tid = threadIdx.x;
    int lane = tid & 63;
    int wv = tid >> 6;
    int wrow = blockIdx.x * 64 + wv * 16;
    int cl = lane & 15, kg = lane >> 4;
    const half8v* Bh = (const half8v*)wf2h;
    const half8v* Bl = (const half8v*)wf2l;
    float4v acc[4] = {};
    int r = wrow + cl;
    long rr = (r < NN) ? r : (NN - 1);
    const half8v* hp = (const half8v*)(h + rr * 64);
#pragma unroll
    for (int kc = 0; kc < 2; ++kc) {
        half8v ah = hp[kc * 4 + kg];
#pragma unroll
        for (int ct = 0; ct < 4; ++ct) {
            half8v bh = Bh[(ct * 2 + kc) * 64 + lane];
            half8v bl = Bl[(ct * 2 + kc) * 64 + lane];
            acc[ct] = __builtin_amdgcn_mfma_f32_16x16x32_f16(ah, bh, acc[ct], 0, 0, 0);
            acc[ct] = __builtin_amdgcn_mfma_f32_16x16x32_f16(ah, bl, acc[ct], 0, 0, 0);
        }
    }
#pragma unroll
    for (int j = 0; j < 4; ++j) {
        int row = wrow + kg * 4 + j;
        if (row < NN) {
            float dv = dis[row];
#pragma unroll
            for (int ct = 0; ct < 4; ++ct)
                t2[(long)row * 64 + ct * 16 + cl] = (_Float16)(acc[ct][j] * dv);
        }
    }
}

// ---------------- fused gather-aggregations ----------------
// 16 lanes per node, 8 B (half4) per lane -> one wave-instruction gathers 4 full
// 128-B rows. 16-deep load batches; masked tail with clamped duplicate loads.
// ds_swizzle BitMode (literal pattern): lane' = (lane & 0x10) | K.

#define SWZ_LD(K) r[K] = t4[(__builtin_amdgcn_ds_swizzle(idx, ((K) << 5) | 0x10) << 4) + j4];

__device__ __forceinline__ void batch16_full(const half4v* __restrict__ t4, int idx,
                                             int j4, float* a) {
    half4v r[16];
    SWZ_LD(0)  SWZ_LD(1)  SWZ_LD(2)  SWZ_LD(3)
    SWZ_LD(4)  SWZ_LD(5)  SWZ_LD(6)  SWZ_LD(7)
    SWZ_LD(8)  SWZ_LD(9)  SWZ_LD(10) SWZ_LD(11)
    SWZ_LD(12) SWZ_LD(13) SWZ_LD(14) SWZ_LD(15)
#pragma unroll
    for (int k = 0; k < 16; ++k) {
        a[0] += (float)r[k][0]; a[1] += (float)r[k][1];
        a[2] += (float)r[k][2]; a[3] += (float)r[k][3];
    }
}

__device__ __forceinline__ void batch16_mask(const half4v* __restrict__ t4, int idx,
                                             int j4, int cnt, float* a) {
    half4v r[16];
    SWZ_LD(0)  SWZ_LD(1)  SWZ_LD(2)  SWZ_LD(3)
    SWZ_LD(4)  SWZ_LD(5)  SWZ_LD(6)  SWZ_LD(7)
    SWZ_LD(8)  SWZ_LD(9)  SWZ_LD(10) SWZ_LD(11)
    SWZ_LD(12) SWZ_LD(13) SWZ_LD(14) SWZ_LD(15)
#pragma unroll
    for (int k = 0; k < 16; ++k) {
        float w = (k < cnt) ? 1.0f : 0.0f;
        a[0] += w * (float)r[k][0]; a[1] += w * (float)r[k][1];
        a[2] += w * (float)r[k][2]; a[3] += w * (float)r[k][3];
    }
}

__device__ __forceinline__ void batch8_mask(const half4v* __restrict__ t4, int idx,
                                            int j4, int cnt, float* a) {
    half4v r[8];
    SWZ_LD(0)  SWZ_LD(1)  SWZ_LD(2)  SWZ_LD(3)
    SWZ_LD(4)  SWZ_LD(5)  SWZ_LD(6)  SWZ_LD(7)
#pragma unroll
    for (int k = 0; k < 8; ++k) {
        float w = (k < cnt) ? 1.0f : 0.0f;
        a[0] += w * (float)r[k][0]; a[1] += w * (float)r[k][1];
        a[2] += w * (float)r[k][2]; a[3] += w * (float)r[k][3];
    }
}

// h[v] = l2normalize(relu(dis[v]*(sum_s t1'[s] + t1'[v]) + b1)), stored fp16
__global__ __launch_bounds__(256) void k_agg1(const half4v* __restrict__ tv4,
                                              const int* __restrict__ row_ptr,
                                              const int* __restrict__ csr_src,
                                              const float* __restrict__ dis,
                                              const float* __restrict__ b1,
                                              _Float16* __restrict__ h) {
    int lane = threadIdx.x & 63;
    int j4 = lane & 15;
    int v = blockIdx.x * 16 + (threadIdx.x >> 6) * 4 + (lane >> 4);  // NN = 6250*16
    int beg = row_ptr[v], end = row_ptr[v + 1];
    float a[4] = {0.f, 0.f, 0.f, 0.f};
    int base = beg;
    for (; base + 16 <= end; base += 16) {
        int idx = csr_src[base + j4];
        batch16_full(tv4, idx, j4, a);
    }
    int cnt = end - base;
    if (cnt > 0) {
        int idx = csr_src[base + ((j4 < cnt) ? j4 : cnt - 1)];
        if (cnt > 8) batch16_mask(tv4, idx, j4, cnt, a);
        else         batch8_mask(tv4, idx, j4, cnt, a);
    }
    float dv = dis[v];
    half4v rv = tv4[(v << 4) + j4];              // = dis[v]*t1[v]
    float4 bb = ((const float4*)b1)[j4];
    float val0 = fmaxf(dv * (a[0] + (float)rv[0]) + bb.x, 0.0f);
    float val1 = fmaxf(dv * (a[1] + (float)rv[1]) + bb.y, 0.0f);
    float val2 = fmaxf(dv * (a[2] + (float)rv[2]) + bb.z, 0.0f);
    float val3 = fmaxf(dv * (a[3] + (float)rv[3]) + bb.w, 0.0f);
    float ss = val0 * val0 + val1 * val1 + val2 * val2 + val3 * val3;
#pragma unroll
    for (int m = 1; m < 16; m <<= 1) ss += __shfl_xor(ss, m);
    float scale = 1.0f / fmaxf(sqrtf(ss), 1e-12f);
    half4v* h4 = (half4v*)h;
    half4v hv;
    hv[0] = (_Float16)(val0 * scale); hv[1] = (_Float16)(val1 * scale);
    hv[2] = (_Float16)(val2 * scale); hv[3] = (_Float16)(val3 * scale);
    h4[(v << 4) + j4] = hv;
}

// layer-2 aggregation fused with bias + reparametrize; writes mu, ls (f32), z (fp16)
__global__ __launch_bounds__(256) void k_agg2(const half4v* __restrict__ tv4,
                                              const int* __restrict__ row_ptr,
                                              const int* __restrict__ csr_src,
                                              const float* __restrict__ dis,
                                              const float* __restrict__ bmu,
                                              const float* __restrict__ bls,
                                              const float* __restrict__ eps,
                                              float* __restrict__ mu,
                                              float* __restrict__ ls,
                                              _Float16* __restrict__ zh) {
    int lane = threadIdx.x & 63;
    int j4 = lane & 15;
    int v = blockIdx.x * 16 + (threadIdx.x >> 6) * 4 + (lane >> 4);
    int beg = row_ptr[v], end = row_ptr[v + 1];
    float a[4] = {0.f, 0.f, 0.f, 0.f};
    int base = beg;
    for (; base + 16 <= end; base += 16) {
        int idx = csr_src[base + j4];
        batch16_full(tv4, idx, j4, a);
    }
    int cnt = end - base;
    if (cnt > 0) {
        int idx = csr_src[base + ((j4 < cnt) ? j4 : cnt - 1)];
        if (cnt > 8) batch16_mask(tv4, idx, j4, cnt, a);
        else         batch8_mask(tv4, idx, j4, cnt, a);
    }
    float dv = dis[v];
    half4v rv = tv4[(v << 4) + j4];              // = dis[v]*t2[v]
    float4 bb = (j4 < 8) ? ((const float4*)bmu)[j4] : ((const float4*)bls)[j4 - 8];
    float val0 = dv * (a[0] + (float)rv[0]) + bb.x;
    float val1 = dv * (a[1] + (float)rv[1]) + bb.y;
    float val2 = dv * (a[2] + (float)rv[2]) + bb.z;
    float val3 = dv * (a[3] + (float)rv[3]) + bb.w;
    // partner lane (j4^8) holds the logstd (resp. mu) for the same dims
    float o0 = __shfl_xor(val0, 8);
    float o1 = __shfl_xor(val1, 8);
    float o2 = __shfl_xor(val2, 8);
    float o3 = __shfl_xor(val3, 8);
    float4v* mu4 = (float4v*)mu;
    float4v* ls4 = (float4v*)ls;
    half4v* z4  = (half4v*)zh;
    const float4* e4 = (const float4*)eps;
    if (j4 < 8) {
        float4v mv; mv.x = val0; mv.y = val1; mv.z = val2; mv.w = val3;
        __builtin_nontemporal_store(mv, &mu4[(v << 3) + j4]);
        float4 ev = e4[(v << 3) + j4];
        float l0 = fminf(fmaxf(o0, -10.0f), 10.0f);
        float l1 = fminf(fmaxf(o1, -10.0f), 10.0f);
        float l2 = fminf(fmaxf(o2, -10.0f), 10.0f);
        float l3 = fminf(fmaxf(o3, -10.0f), 10.0f);
        half4v zw;
        zw[0] = (_Float16)(val0 + ev.x * expf(l0));
        zw[1] = (_Float16)(val1 + ev.y * expf(l1));
        zw[2] = (_Float16)(val2 + ev.z * expf(l2));
        zw[3] = (_Float16)(val3 + ev.w * expf(l3));
        z4[(v << 3) + j4] = zw;
    } else {
        float4v lv; lv.x = val0; lv.y = val1; lv.z = val2; lv.w = val3;
        __builtin_nontemporal_store(lv, &ls4[(v << 3) + (j4 - 8)]);
    }
}

// ---------------- bucket-ordered decode ----------------
// One block per 128-node dst bucket: stage the bucket's 128 z-rows (8 KB) in LDS,
// stream ebuf/eid (bucket order, intact from k_place): dst row from LDS, z[src]
// random 64-B row, out[eid[p]] 4-B scatter. Random z line-touches: 3.2M -> 1.6M.
// Wave = 8 groups x 8 lanes; group g handles one edge, lane j dims [4j,4j+4).
__global__ __launch_bounds__(256) void k_decode(const _Float16* __restrict__ zh,
                                                const int* __restrict__ bucket_base,
                                                const int* __restrict__ ebuf,
                                                const int* __restrict__ eid,
                                                float* __restrict__ out) {
    __shared__ _Float16 zl[W_BKT * 32];               // 8 KB
    int b = blockIdx.x;
    int tid = threadIdx.x;
    int base_node = b * W_BKT;
    int nrows = NN - base_node; if (nrows > W_BKT) nrows = W_BKT;
    {
        const float4* zsrc = (const float4*)(zh + (long)base_node * 32);
        float4* zdst = (float4*)zl;
        for (int i = tid; i < nrows * 4; i += 256) zdst[i] = zsrc[i];
    }
    __syncthreads();
    int beg = bucket_base[b], end = bucket_base[b + 1];
    int lane = tid & 63;
    int g = lane >> 3, j = lane & 7;
    int wv = tid >> 6;
    const half4v* z4 = (const half4v*)zh;
    const half4v* zl4 = (const half4v*)zl;
    for (int base = beg + wv * 8; base < end; base += 32) {
        int cnt = end - base; if (cnt > 8) cnt = 8;
        int p = base + ((g < cnt) ? g : cnt - 1);     // clamped duplicate
        int val = ebuf[p];
        int s = val >> 7, dloc = val & 127;
        half4v za = z4[((long)s << 3) + j];           // random 64-B row
        half4v zv = zl4[(dloc << 3) + j];             // LDS
        float d = (float)za[0] * (float)zv[0] + (float)za[1] * (float)zv[1] +
                  (float)za[2] * (float)zv[2] + (float)za[3] * (float)zv[3];
        d += __shfl_xor(d, 1);
        d += __shfl_xor(d, 2);
        d += __shfl_xor(d, 4);
        if (j == 0 && g < cnt)
            out[eid[p]] = 1.0f / (1.0f + expf(-d));
    }
}

extern "C" void kernel_launch(void* const* d_in, const int* in_sizes, int n_in,
                              void* d_out, int out_size, void* d_ws, size_t ws_size,
                              hipStream_t stream) {
    const float* x   = (const float*)d_in[0];
    const int*   ei  = (const int*)d_in[1];
    const float* eps = (const float*)d_in[2];
    const float* W1  = (const float*)d_in[3];
    const float* b1  = (const float*)d_in[4];
    const float* Wmu = (const float*)d_in[5];
    const float* bmu = (const float*)d_in[6];
    const float* Wls = (const float*)d_in[7];
    const float* bls = (const float*)d_in[8];
    const int* src = ei;        // edge_index[0]
    const int* dst = ei + NE;   // edge_index[1]

    float* out = (float*)d_out;
    float* adj = out;                       // [E]
    float* mu  = out + NE;                  // [N,32]
    float* ls  = mu + (long)NN * 32;        // [N,32]

    // workspace layout (all block byte sizes multiples of 16; zh 64B-aligned)
    float* dis      = (float*)d_ws;              // NN
    int*   row_ptr  = (int*)(dis + NN);          // 100004
    int*   bucket_base = row_ptr + 100004;       // NB_BKT+1 -> pad 784
    int*   counts   = bucket_base + 784;         // NT*NB_BKT = 76636 -> pad 76640
    int*   ebuf     = counts + 76640;            // NE (kept through decode)
    int*   csr_src  = ebuf + NE;                 // NE
    int*   eid      = csr_src + NE;              // NE (bucket-order edge ids)
    _Float16* t     = (_Float16*)(eid + NE);     // NN*64 fp16 (t1' then t2')
    _Float16* h     = t + (long)NN * 64;         // NN*64 fp16
    _Float16* zh    = h + (long)NN * 64 + 24;    // NN*32 fp16, 64B-aligned

    // W fragment tables alias the counts region (dead after k_place; k_wprep is
    // stream-ordered after k_place). 49152 B << 306 KB region, 16B-aligned.
    _Float16* wf1h = (_Float16*)counts;          // 16x64x8 = 8192 f16
    _Float16* wf1l = wf1h + 8192;                // 8192
    _Float16* wf2h = wf1l + 8192;                // 8x64x8 = 4096
    _Float16* wf2l = wf2h + 4096;                // 4096

    const int B = 256;

    // CSR + deg/dis build — zero global atomics
    k_cnt  <<<NT, B, 0, stream>>>(dst, counts);
    k_bscan<<<1, 1024, 0, stream>>>(counts, bucket_base);   // scan + tile offsets
    k_place<<<NT, B, 0, stream>>>(src, dst, counts, ebuf, eid);
    k_wprep<<<1, B, 0, stream>>>(W1, Wmu, Wls, wf1h, wf1l, wf2h, wf2l);
    k_build<<<NB_BKT, B, 0, stream>>>(bucket_base, ebuf, csr_src, row_ptr, dis);

    // layer 1
    k_gemm1<<<(NN + 63) / 64, B, 0, stream>>>(x, wf1h, wf1l, dis, t);
    k_agg1 <<<NN / 16, B, 0, stream>>>((const half4v*)t, row_ptr, csr_src, dis, b1, h);

    // layer 2
    k_gemm2<<<(NN + 63) / 64, B, 0, stream>>>(h, wf2h, wf2l, dis, t);
    k_agg2 <<<NN / 16, B, 0, stream>>>((const half4v*)t, row_ptr, csr_src, dis,
                                       bmu, bls, eps, mu, ls, zh);

    // decode (bucket order: z[dst] staged in LDS, scatter via eid)
    k_decode<<<NB_BKT, B, 0, stream>>>(zh, bucket_base, ebuf, eid, adj);
}

// Round 9
// 409.150 us; speedup vs baseline: 1.0739x; 1.0739x over previous
//
#include <hip/hip_runtime.h>
#include <hip/hip_fp16.h>

#define NN 100000
#define NE 1600000
#define W_BKT 128
#define NB_BKT ((NN + W_BKT - 1) / W_BKT)   // 782
#define TILE_E 16384                         // edges per counting-sort tile
#define NT ((NE + TILE_E - 1) / TILE_E)      // 98
#define STAGE_CAP 4352                       // LDS staging (avg bucket ~2048)
// IN=128, HID=64, OUT=32

typedef _Float16 half2v __attribute__((ext_vector_type(2)));
typedef _Float16 half4v __attribute__((ext_vector_type(4)));
typedef _Float16 half8v __attribute__((ext_vector_type(8)));
typedef float float2v __attribute__((ext_vector_type(2)));
typedef float float4v __attribute__((ext_vector_type(4)));

// ---- deterministic two-pass bucket sort + fused CSR/deg build (NO global atomics) ----

__global__ __launch_bounds__(256) void k_cnt(const int* __restrict__ dst,
                                             int* __restrict__ counts) {
    __shared__ int hc[NB_BKT];
    int tid = threadIdx.x;
    for (int i = tid; i < NB_BKT; i += 256) hc[i] = 0;
    __syncthreads();
    int base = blockIdx.x * TILE_E;
    int lim = base + TILE_E; if (lim > NE) lim = NE;
    for (int e = base + tid; e < lim; e += 256)
        atomicAdd(&hc[dst[e] >> 7], 1);
    __syncthreads();
    for (int i = tid; i < NB_BKT; i += 256)
        counts[blockIdx.x * NB_BKT + i] = hc[i];
}

// scan bucket totals -> bucket_base, AND convert counts to per-tile offsets
__global__ __launch_bounds__(1024) void k_bscan(int* __restrict__ counts,
                                                int* __restrict__ bucket_base) {
    __shared__ int buf[1024];
    int tid = threadIdx.x;
    int total = 0;
    if (tid < NB_BKT)
        for (int t = 0; t < NT; ++t) total += counts[t * NB_BKT + tid];
    buf[tid] = total;
    __syncthreads();
    for (int off = 1; off < 1024; off <<= 1) {
        int v = (tid >= off) ? buf[tid - off] : 0;
        __syncthreads();
        buf[tid] += v;
        __syncthreads();
    }
    if (tid < NB_BKT) {
        int off = buf[tid] - total;              // exclusive prefix
        bucket_base[tid] = off;
        for (int t = 0; t < NT; ++t) {
            int c = counts[t * NB_BKT + tid];
            counts[t * NB_BKT + tid] = off;
            off += c;
        }
    }
    if (tid == 0) bucket_base[NB_BKT] = NE;
}

// place edges into dst-bucket order; record original edge id (bucket order, used by decode)
__global__ __launch_bounds__(256) void k_place(const int* __restrict__ src,
                                               const int* __restrict__ dst,
                                               const int* __restrict__ counts,
                                               int* __restrict__ ebuf,
                                               int* __restrict__ eid) {
    __shared__ int cur[NB_BKT];
    int tid = threadIdx.x;
    for (int i = tid; i < NB_BKT; i += 256)
        cur[i] = counts[blockIdx.x * NB_BKT + i];
    __syncthreads();
    int base = blockIdx.x * TILE_E;
    int lim = base + TILE_E; if (lim > NE) lim = NE;
    for (int e = base + tid; e < lim; e += 256) {
        int s = src[e], d = dst[e];
        int pos = atomicAdd(&cur[d >> 7], 1);     // LDS atomic
        ebuf[pos] = (s << 7) | (d & 127);
        eid[pos] = e;
    }
}

// one block per bucket: LDS-stage the bucket's ebuf slice, count 128 node degs,
// prefix-scan -> row_ptr + dis, then scatter to csr_src. (ebuf/eid stay intact.)
__global__ __launch_bounds__(256) void k_build(const int* __restrict__ bucket_base,
                                               const int* __restrict__ ebuf,
                                               int* __restrict__ csr_src,
                                               int* __restrict__ row_ptr,
                                               float* __restrict__ dis) {
    __shared__ int deg[W_BKT];
    __shared__ int pre[W_BKT];
    __shared__ int cur[W_BKT];
    __shared__ int stage[STAGE_CAP];
    int b = blockIdx.x;
    int tid = threadIdx.x;
    int beg = bucket_base[b], end = bucket_base[b + 1];
    int n = end - beg;
    if (tid < W_BKT) deg[tid] = 0;
    __syncthreads();
    bool fits = (n <= STAGE_CAP);
    if (fits) {
        for (int i = tid; i < n; i += 256) {
            int val = ebuf[beg + i];
            stage[i] = val;
            atomicAdd(&deg[val & 127], 1);
        }
    } else {
        for (int i = tid; i < n; i += 256)
            atomicAdd(&deg[ebuf[beg + i] & 127], 1);
    }
    __syncthreads();
    if (tid < W_BKT) pre[tid] = deg[tid];
    __syncthreads();
    for (int off = 1; off < W_BKT; off <<= 1) {
        int v = (tid >= off && tid < W_BKT) ? pre[tid - off] : 0;
        __syncthreads();
        if (tid < W_BKT) pre[tid] += v;
        __syncthreads();
    }
    if (tid < W_BKT) {
        int v = b * W_BKT + tid;
        int rp = beg + pre[tid] - deg[tid];      // exclusive prefix
        if (v < NN) {
            row_ptr[v] = rp;
            dis[v] = rsqrtf((float)(1 + deg[tid]));
        }
        cur[tid] = rp;
    }
    if (b == NB_BKT - 1 && tid == 0) row_ptr[NN] = NE;
    __syncthreads();
    if (fits) {
        for (int i = tid; i < n; i += 256) {
            int val = stage[i];
            int pos = atomicAdd(&cur[val & 127], 1);
            csr_src[pos] = val >> 7;
        }
    } else {
        for (int i = tid; i < n; i += 256) {
            int val = ebuf[beg + i];
            int pos = atomicAdd(&cur[val & 127], 1);
            csr_src[pos] = val >> 7;
        }
    }
}

// ---------------- dense transforms via MFMA (dis folded into stored rows) ----------------
// W pre-packed into fragment-ordered f16 hi/lo tables. GEMM1: Ah*Bh+Al*Bh+Ah*Bl
// (fp32-equivalent). GEMM2 input h is fp16 (exact) -> Ah*Bh+Ah*Bl only.

__global__ __launch_bounds__(256) void k_wprep(const float* __restrict__ W1,
                                               const float* __restrict__ Wmu,
                                               const float* __restrict__ Wls,
                                               _Float16* __restrict__ wf1h,
                                               _Float16* __restrict__ wf1l,
                                               _Float16* __restrict__ wf2h,
                                               _Float16* __restrict__ wf2l) {
    int tid = threadIdx.x;
    for (int f = tid; f < 4 * 4 * 64; f += 256) {
        int lane = f & 63;
        int kc = (f >> 6) & 3;
        int ct = f >> 8;
        int col = ct * 16 + (lane & 15);
        int k0 = kc * 32 + (lane >> 4) * 8;
#pragma unroll
        for (int j = 0; j < 8; ++j) {
            float w = W1[(k0 + j) * 64 + col];
            _Float16 hi = (_Float16)w;
            wf1h[f * 8 + j] = hi;
            wf1l[f * 8 + j] = (_Float16)(w - (float)hi);
        }
    }
    for (int f = tid; f < 4 * 2 * 64; f += 256) {
        int lane = f & 63;
        int kc = (f >> 6) & 1;
        int ct = f >> 7;
        int col = ct * 16 + (lane & 15);
        int k0 = kc * 32 + (lane >> 4) * 8;
#pragma unroll
        for (int j = 0; j < 8; ++j) {
            int k = k0 + j;
            float w = (col < 32) ? Wmu[k * 32 + col] : Wls[k * 32 + (col - 32)];
            _Float16 hi = (_Float16)w;
            wf2h[f * 8 + j] = hi;
            wf2l[f * 8 + j] = (_Float16)(w - (float)hi);
        }
    }
}

__device__ __forceinline__ void split8(const float4 a, const float4 b,
                                       half8v& hi, half8v& lo) {
    float v[8] = {a.x, a.y, a.z, a.w, b.x, b.y, b.z, b.w};
#pragma unroll
    for (int i = 0; i < 8; ++i) {
        _Float16 h = (_Float16)v[i];
        hi[i] = h;
        lo[i] = (_Float16)(v[i] - (float)h);
    }
}

// t1'[v] = dis[v] * (x[v] @ W1), stored fp16. 64 rows/block, 16 rows/wave, no LDS.
__global__ __launch_bounds__(256) void k_gemm1(const float* __restrict__ x,
                                               const _Float16* __restrict__ wf1h,
                                               const _Float16* __restrict__ wf1l,
                                               const float* __restrict__ dis,
                                               _Float16* __restrict__ t1) {
    int tid = threadIdx.x;
    int lane = tid & 63;
    int wv = tid >> 6;
    int wrow = blockIdx.x * 64 + wv * 16;
    int cl = lane & 15, kg = lane >> 4;
    const half8v* Bh = (const half8v*)wf1h;
    const half8v* Bl = (const half8v*)wf1l;
    float4v acc[4] = {};
    int r = wrow + cl;
    long rr = (r < NN) ? r : (NN - 1);
    const float4* xp = (const float4*)(x + rr * 128);
#pragma unroll
    for (int kc = 0; kc < 4; ++kc) {
        float4 xa = xp[kc * 8 + kg * 2];
        float4 xb = xp[kc * 8 + kg * 2 + 1];
        half8v ah, al;
        split8(xa, xb, ah, al);
#pragma unroll
        for (int ct = 0; ct < 4; ++ct) {
            half8v bh = Bh[(ct * 4 + kc) * 64 + lane];
            half8v bl = Bl[(ct * 4 + kc) * 64 + lane];
            acc[ct] = __builtin_amdgcn_mfma_f32_16x16x32_f16(ah, bh, acc[ct], 0, 0, 0);
            acc[ct] = __builtin_amdgcn_mfma_f32_16x16x32_f16(al, bh, acc[ct], 0, 0, 0);
            acc[ct] = __builtin_amdgcn_mfma_f32_16x16x32_f16(ah, bl, acc[ct], 0, 0, 0);
        }
    }
#pragma unroll
    for (int j = 0; j < 4; ++j) {
        int row = wrow + kg * 4 + j;
        if (row < NN) {
            float dv = dis[row];
#pragma unroll
            for (int ct = 0; ct < 4; ++ct)
                t1[(long)row * 64 + ct * 16 + cl] = (_Float16)(acc[ct][j] * dv);
        }
    }
}

// t2'[v] = dis[v] * (h[v] @ [Wmu | Wls]), h fp16 input, stored fp16
__global__ __launch_bounds__(256) void k_gemm2(const _Float16* __restrict__ h,
                                               const _Float16* __restrict__ wf2h,
                                               const _Float16* __restrict__ wf2l,
                                               const float* __restrict__ dis,
                                               _Float16* __restrict__ t2) {
    int tid = threadIdx.x;
    int lane = tid & 63;
    int wv = tid >> 6;
    int wrow = blockIdx.x * 64 + wv * 16;
    int cl = lane & 15, kg = lane >> 4;
    const half8v* Bh = (const half8v*)wf2h;
    const half8v* Bl = (const half8v*)wf2l;
    float4v acc[4] = {};
    int r = wrow + cl;
    long rr = (r < NN) ? r : (NN - 1);
    const half8v* hp = (const half8v*)(h + rr * 64);
#pragma unroll
    for (int kc = 0; kc < 2; ++kc) {
        half8v ah = hp[kc * 4 + kg];
#pragma unroll
        for (int ct = 0; ct < 4; ++ct) {
            half8v bh = Bh[(ct * 2 + kc) * 64 + lane];
            half8v bl = Bl[(ct * 2 + kc) * 64 + lane];
            acc[ct] = __builtin_amdgcn_mfma_f32_16x16x32_f16(ah, bh, acc[ct], 0, 0, 0);
            acc[ct] = __builtin_amdgcn_mfma_f32_16x16x32_f16(ah, bl, acc[ct], 0, 0, 0);
        }
    }
#pragma unroll
    for (int j = 0; j < 4; ++j) {
        int row = wrow + kg * 4 + j;
        if (row < NN) {
            float dv = dis[row];
#pragma unroll
            for (int ct = 0; ct < 4; ++ct)
                t2[(long)row * 64 + ct * 16 + cl] = (_Float16)(acc[ct][j] * dv);
        }
    }
}

// ---------------- fused gather-aggregations ----------------
// 16 lanes per node, 8 B (half4) per lane -> one wave-instruction gathers 4 full
// 128-B rows. 16-deep load batches; masked tail with clamped duplicate loads.
// ds_swizzle BitMode (literal pattern): lane' = (lane & 0x10) | K.

#define SWZ_LD(K) r[K] = t4[(__builtin_amdgcn_ds_swizzle(idx, ((K) << 5) | 0x10) << 4) + j4];

__device__ __forceinline__ void batch16_full(const half4v* __restrict__ t4, int idx,
                                             int j4, float* a) {
    half4v r[16];
    SWZ_LD(0)  SWZ_LD(1)  SWZ_LD(2)  SWZ_LD(3)
    SWZ_LD(4)  SWZ_LD(5)  SWZ_LD(6)  SWZ_LD(7)
    SWZ_LD(8)  SWZ_LD(9)  SWZ_LD(10) SWZ_LD(11)
    SWZ_LD(12) SWZ_LD(13) SWZ_LD(14) SWZ_LD(15)
#pragma unroll
    for (int k = 0; k < 16; ++k) {
        a[0] += (float)r[k][0]; a[1] += (float)r[k][1];
        a[2] += (float)r[k][2]; a[3] += (float)r[k][3];
    }
}

__device__ __forceinline__ void batch16_mask(const half4v* __restrict__ t4, int idx,
                                             int j4, int cnt, float* a) {
    half4v r[16];
    SWZ_LD(0)  SWZ_LD(1)  SWZ_LD(2)  SWZ_LD(3)
    SWZ_LD(4)  SWZ_LD(5)  SWZ_LD(6)  SWZ_LD(7)
    SWZ_LD(8)  SWZ_LD(9)  SWZ_LD(10) SWZ_LD(11)
    SWZ_LD(12) SWZ_LD(13) SWZ_LD(14) SWZ_LD(15)
#pragma unroll
    for (int k = 0; k < 16; ++k) {
        float w = (k < cnt) ? 1.0f : 0.0f;
        a[0] += w * (float)r[k][0]; a[1] += w * (float)r[k][1];
        a[2] += w * (float)r[k][2]; a[3] += w * (float)r[k][3];
    }
}

__device__ __forceinline__ void batch8_mask(const half4v* __restrict__ t4, int idx,
                                            int j4, int cnt, float* a) {
    half4v r[8];
    SWZ_LD(0)  SWZ_LD(1)  SWZ_LD(2)  SWZ_LD(3)
    SWZ_LD(4)  SWZ_LD(5)  SWZ_LD(6)  SWZ_LD(7)
#pragma unroll
    for (int k = 0; k < 8; ++k) {
        float w = (k < cnt) ? 1.0f : 0.0f;
        a[0] += w * (float)r[k][0]; a[1] += w * (float)r[k][1];
        a[2] += w * (float)r[k][2]; a[3] += w * (float)r[k][3];
    }
}

// h[v] = l2normalize(relu(dis[v]*(sum_s t1'[s] + t1'[v]) + b1)), stored fp16
__global__ __launch_bounds__(256) void k_agg1(const half4v* __restrict__ tv4,
                                              const int* __restrict__ row_ptr,
                                              const int* __restrict__ csr_src,
                                              const float* __restrict__ dis,
                                              const float* __restrict__ b1,
                                              _Float16* __restrict__ h) {
    int lane = threadIdx.x & 63;
    int j4 = lane & 15;
    int v = blockIdx.x * 16 + (threadIdx.x >> 6) * 4 + (lane >> 4);  // NN = 6250*16
    int beg = row_ptr[v], end = row_ptr[v + 1];
    float a[4] = {0.f, 0.f, 0.f, 0.f};
    int base = beg;
    for (; base + 16 <= end; base += 16) {
        int idx = csr_src[base + j4];
        batch16_full(tv4, idx, j4, a);
    }
    int cnt = end - base;
    if (cnt > 0) {
        int idx = csr_src[base + ((j4 < cnt) ? j4 : cnt - 1)];
        if (cnt > 8) batch16_mask(tv4, idx, j4, cnt, a);
        else         batch8_mask(tv4, idx, j4, cnt, a);
    }
    float dv = dis[v];
    half4v rv = tv4[(v << 4) + j4];              // = dis[v]*t1[v]
    float4 bb = ((const float4*)b1)[j4];
    float val0 = fmaxf(dv * (a[0] + (float)rv[0]) + bb.x, 0.0f);
    float val1 = fmaxf(dv * (a[1] + (float)rv[1]) + bb.y, 0.0f);
    float val2 = fmaxf(dv * (a[2] + (float)rv[2]) + bb.z, 0.0f);
    float val3 = fmaxf(dv * (a[3] + (float)rv[3]) + bb.w, 0.0f);
    float ss = val0 * val0 + val1 * val1 + val2 * val2 + val3 * val3;
#pragma unroll
    for (int m = 1; m < 16; m <<= 1) ss += __shfl_xor(ss, m);
    float scale = 1.0f / fmaxf(sqrtf(ss), 1e-12f);
    half4v* h4 = (half4v*)h;
    half4v hv;
    hv[0] = (_Float16)(val0 * scale); hv[1] = (_Float16)(val1 * scale);
    hv[2] = (_Float16)(val2 * scale); hv[3] = (_Float16)(val3 * scale);
    h4[(v << 4) + j4] = hv;
}

// layer-2 aggregation fused with bias + reparametrize; writes mu, ls (f32), z (fp16)
__global__ __launch_bounds__(256) void k_agg2(const half4v* __restrict__ tv4,
                                              const int* __restrict__ row_ptr,
                                              const int* __restrict__ csr_src,
                                              const float* __restrict__ dis,
                                              const float* __restrict__ bmu,
                                              const float* __restrict__ bls,
                                              const float* __restrict__ eps,
                                              float* __restrict__ mu,
                                              float* __restrict__ ls,
                                              _Float16* __restrict__ zh) {
    int lane = threadIdx.x & 63;
    int j4 = lane & 15;
    int v = blockIdx.x * 16 + (threadIdx.x >> 6) * 4 + (lane >> 4);
    int beg = row_ptr[v], end = row_ptr[v + 1];
    float a[4] = {0.f, 0.f, 0.f, 0.f};
    int base = beg;
    for (; base + 16 <= end; base += 16) {
        int idx = csr_src[base + j4];
        batch16_full(tv4, idx, j4, a);
    }
    int cnt = end - base;
    if (cnt > 0) {
        int idx = csr_src[base + ((j4 < cnt) ? j4 : cnt - 1)];
        if (cnt > 8) batch16_mask(tv4, idx, j4, cnt, a);
        else         batch8_mask(tv4, idx, j4, cnt, a);
    }
    float dv = dis[v];
    half4v rv = tv4[(v << 4) + j4];              // = dis[v]*t2[v]
    float4 bb = (j4 < 8) ? ((const float4*)bmu)[j4] : ((const float4*)bls)[j4 - 8];
    float val0 = dv * (a[0] + (float)rv[0]) + bb.x;
    float val1 = dv * (a[1] + (float)rv[1]) + bb.y;
    float val2 = dv * (a[2] + (float)rv[2]) + bb.z;
    float val3 = dv * (a[3] + (float)rv[3]) + bb.w;
    // partner lane (j4^8) holds the logstd (resp. mu) for the same dims
    float o0 = __shfl_xor(val0, 8);
    float o1 = __shfl_xor(val1, 8);
    float o2 = __shfl_xor(val2, 8);
    float o3 = __shfl_xor(val3, 8);
    float4v* mu4 = (float4v*)mu;
    float4v* ls4 = (float4v*)ls;
    half4v* z4  = (half4v*)zh;
    const float4* e4 = (const float4*)eps;
    if (j4 < 8) {
        float4v mv; mv.x = val0; mv.y = val1; mv.z = val2; mv.w = val3;
        __builtin_nontemporal_store(mv, &mu4[(v << 3) + j4]);
        float4 ev = e4[(v << 3) + j4];
        float l0 = fminf(fmaxf(o0, -10.0f), 10.0f);
        float l1 = fminf(fmaxf(o1, -10.0f), 10.0f);
        float l2 = fminf(fmaxf(o2, -10.0f), 10.0f);
        float l3 = fminf(fmaxf(o3, -10.0f), 10.0f);
        half4v zw;
        zw[0] = (_Float16)(val0 + ev.x * expf(l0));
        zw[1] = (_Float16)(val1 + ev.y * expf(l1));
        zw[2] = (_Float16)(val2 + ev.z * expf(l2));
        zw[3] = (_Float16)(val3 + ev.w * expf(l3));
        z4[(v << 3) + j4] = zw;
    } else {
        float4v lv; lv.x = val0; lv.y = val1; lv.z = val2; lv.w = val3;
        __builtin_nontemporal_store(lv, &ls4[(v << 3) + (j4 - 8)]);
    }
}

// ---------------- bucket-ordered decode v2 (no LDS, MLP-restored) ----------------
// 4 blocks per bucket; dst rows live in an 8-KB window -> L1/L2 hits from global
// (no staging, no bank conflicts). 4 lanes/edge, half8 (16-B) loads, 4-edge batch
// per group -> 8 z-loads + 8 index loads in flight per lane. Clamped-duplicate
// tail with masked store. Random z line-touches stay halved (src only).
__global__ __launch_bounds__(256) void k_decode(const _Float16* __restrict__ zh,
                                                const int* __restrict__ bucket_base,
                                                const int* __restrict__ ebuf,
                                                const int* __restrict__ eid,
                                                float* __restrict__ out) {
    int blk = blockIdx.x;
    int b = blk >> 2, part = blk & 3;
    int beg0 = bucket_base[b], end0 = bucket_base[b + 1];
    int n = end0 - beg0;
    int qsz = (n + 3) >> 2;
    int beg = beg0 + part * qsz;
    int end = beg + qsz; if (end > end0) end = end0;
    long zb = (long)b * W_BKT * 4;                 // dst-row base (half8 units)
    int j = threadIdx.x & 3;                       // dim slice [8j, 8j+8)
    int gi = threadIdx.x >> 2;                     // group id in block [0,64)
    const half8v* z8 = (const half8v*)zh;
    for (int p0 = beg + gi * 4; p0 < end; p0 += 256) {
        int cnt = end - p0; if (cnt > 4) cnt = 4;
        int p[4], val[4], id[4];
#pragma unroll
        for (int k = 0; k < 4; ++k) p[k] = p0 + ((k < cnt) ? k : cnt - 1);
#pragma unroll
        for (int k = 0; k < 4; ++k) { val[k] = ebuf[p[k]]; id[k] = eid[p[k]]; }
        half8v za[4], zd[4];
#pragma unroll
        for (int k = 0; k < 4; ++k) {
            za[k] = z8[(long)(val[k] >> 7) * 4 + j];        // random 64-B row (src)
            zd[k] = z8[zb + (long)(val[k] & 127) * 4 + j];  // hot 8-KB window (dst)
        }
#pragma unroll
        for (int k = 0; k < 4; ++k) {
            float d = 0.f;
#pragma unroll
            for (int i = 0; i < 8; ++i) d += (float)za[k][i] * (float)zd[k][i];
            d += __shfl_xor(d, 1);
            d += __shfl_xor(d, 2);
            if (j == 0 && k < cnt)
                out[id[k]] = 1.0f / (1.0f + expf(-d));
        }
    }
}

extern "C" void kernel_launch(void* const* d_in, const int* in_sizes, int n_in,
                              void* d_out, int out_size, void* d_ws, size_t ws_size,
                              hipStream_t stream) {
    const float* x   = (const float*)d_in[0];
    const int*   ei  = (const int*)d_in[1];
    const float* eps = (const float*)d_in[2];
    const float* W1  = (const float*)d_in[3];
    const float* b1  = (const float*)d_in[4];
    const float* Wmu = (const float*)d_in[5];
    const float* bmu = (const float*)d_in[6];
    const float* Wls = (const float*)d_in[7];
    const float* bls = (const float*)d_in[8];
    const int* src = ei;        // edge_index[0]
    const int* dst = ei + NE;   // edge_index[1]

    float* out = (float*)d_out;
    float* adj = out;                       // [E]
    float* mu  = out + NE;                  // [N,32]
    float* ls  = mu + (long)NN * 32;        // [N,32]

    // workspace layout (all block byte sizes multiples of 16; zh 64B-aligned)
    float* dis      = (float*)d_ws;              // NN
    int*   row_ptr  = (int*)(dis + NN);          // 100004
    int*   bucket_base = row_ptr + 100004;       // NB_BKT+1 -> pad 784
    int*   counts   = bucket_base + 784;         // NT*NB_BKT = 76636 -> pad 76640
    int*   ebuf     = counts + 76640;            // NE (kept through decode)
    int*   csr_src  = ebuf + NE;                 // NE
    int*   eid      = csr_src + NE;              // NE (bucket-order edge ids)
    _Float16* t     = (_Float16*)(eid + NE);     // NN*64 fp16 (t1' then t2')
    _Float16* h     = t + (long)NN * 64;         // NN*64 fp16
    _Float16* zh    = h + (long)NN * 64 + 24;    // NN*32 fp16, 64B-aligned

    // W fragment tables alias the counts region (dead after k_place; k_wprep is
    // stream-ordered after k_place). 49152 B << 306 KB region, 16B-aligned.
    _Float16* wf1h = (_Float16*)counts;          // 16x64x8 = 8192 f16
    _Float16* wf1l = wf1h + 8192;                // 8192
    _Float16* wf2h = wf1l + 8192;                // 8x64x8 = 4096
    _Float16* wf2l = wf2h + 4096;                // 4096

    const int B = 256;

    // CSR + deg/dis build — zero global atomics
    k_cnt  <<<NT, B, 0, stream>>>(dst, counts);
    k_bscan<<<1, 1024, 0, stream>>>(counts, bucket_base);   // scan + tile offsets
    k_place<<<NT, B, 0, stream>>>(src, dst, counts, ebuf, eid);
    k_wprep<<<1, B, 0, stream>>>(W1, Wmu, Wls, wf1h, wf1l, wf2h, wf2l);
    k_build<<<NB_BKT, B, 0, stream>>>(bucket_base, ebuf, csr_src, row_ptr, dis);

    // layer 1
    k_gemm1<<<(NN + 63) / 64, B, 0, stream>>>(x, wf1h, wf1l, dis, t);
    k_agg1 <<<NN / 16, B, 0, stream>>>((const half4v*)t, row_ptr, csr_src, dis, b1, h);

    // layer 2
    k_gemm2<<<(NN + 63) / 64, B, 0, stream>>>(h, wf2h, wf2l, dis, t);
    k_agg2 <<<NN / 16, B, 0, stream>>>((const half4v*)t, row_ptr, csr_src, dis,
                                       bmu, bls, eps, mu, ls, zh);

    // decode (bucket order, 4 blocks/bucket, dst rows via cache, scatter via eid)
    k_decode<<<NB_BKT * 4, B, 0, stream>>>(zh, bucket_base, ebuf, eid, adj);
}

// Round 10
// 373.809 us; speedup vs baseline: 1.1754x; 1.0945x over previous
//
#include <hip/hip_runtime.h>
#include <hip/hip_fp16.h>

#define NN 100000
#define NE 1600000
#define W_BKT 128
#define NB_BKT ((NN + W_BKT - 1) / W_BKT)   // 782
#define TILE_E 16384                         // edges per counting-sort tile
#define NT ((NE + TILE_E - 1) / TILE_E)      // 98
#define STAGE_CAP 4352                       // LDS staging (avg bucket ~2048)
// IN=128, HID=64, OUT=32

typedef _Float16 half2v __attribute__((ext_vector_type(2)));
typedef _Float16 half4v __attribute__((ext_vector_type(4)));
typedef _Float16 half8v __attribute__((ext_vector_type(8)));
typedef float float2v __attribute__((ext_vector_type(2)));
typedef float float4v __attribute__((ext_vector_type(4)));

// ---- deterministic two-pass bucket sort + fused CSR/deg build (NO global atomics) ----

__global__ __launch_bounds__(256) void k_cnt(const int* __restrict__ dst,
                                             int* __restrict__ counts) {
    __shared__ int hc[NB_BKT];
    int tid = threadIdx.x;
    for (int i = tid; i < NB_BKT; i += 256) hc[i] = 0;
    __syncthreads();
    int base = blockIdx.x * TILE_E;
    int lim = base + TILE_E; if (lim > NE) lim = NE;
    for (int e = base + tid; e < lim; e += 256)
        atomicAdd(&hc[dst[e] >> 7], 1);
    __syncthreads();
    for (int i = tid; i < NB_BKT; i += 256)
        counts[blockIdx.x * NB_BKT + i] = hc[i];
}

// scan bucket totals -> bucket_base, AND convert counts to per-tile offsets
__global__ __launch_bounds__(1024) void k_bscan(int* __restrict__ counts,
                                                int* __restrict__ bucket_base) {
    __shared__ int buf[1024];
    int tid = threadIdx.x;
    int total = 0;
    if (tid < NB_BKT)
        for (int t = 0; t < NT; ++t) total += counts[t * NB_BKT + tid];
    buf[tid] = total;
    __syncthreads();
    for (int off = 1; off < 1024; off <<= 1) {
        int v = (tid >= off) ? buf[tid - off] : 0;
        __syncthreads();
        buf[tid] += v;
        __syncthreads();
    }
    if (tid < NB_BKT) {
        int off = buf[tid] - total;              // exclusive prefix
        bucket_base[tid] = off;
        for (int t = 0; t < NT; ++t) {
            int c = counts[t * NB_BKT + tid];
            counts[t * NB_BKT + tid] = off;
            off += c;
        }
    }
    if (tid == 0) bucket_base[NB_BKT] = NE;
}

// place edges into dst-bucket order; (val, edge-id) packed in one int2 8-B store.
// 1024 threads: 16 waves/block to hide scattered-store latency.
__global__ __launch_bounds__(1024) void k_place(const int* __restrict__ src,
                                                const int* __restrict__ dst,
                                                const int* __restrict__ counts,
                                                int2* __restrict__ ebuf2) {
    __shared__ int cur[NB_BKT];
    int tid = threadIdx.x;
    for (int i = tid; i < NB_BKT; i += 1024)
        cur[i] = counts[blockIdx.x * NB_BKT + i];
    __syncthreads();
    int base = blockIdx.x * TILE_E;
    int lim = base + TILE_E; if (lim > NE) lim = NE;
    for (int e = base + tid; e < lim; e += 1024) {
        int s = src[e], d = dst[e];
        int pos = atomicAdd(&cur[d >> 7], 1);     // LDS atomic
        ebuf2[pos] = make_int2((s << 7) | (d & 127), e);
    }
}

// one block per bucket: LDS-stage the bucket's vals, count 128 node degs,
// prefix-scan -> row_ptr + dis, then scatter to csr_src. (ebuf2 stays intact.)
__global__ __launch_bounds__(256) void k_build(const int* __restrict__ bucket_base,
                                               const int2* __restrict__ ebuf2,
                                               int* __restrict__ csr_src,
                                               int* __restrict__ row_ptr,
                                               float* __restrict__ dis) {
    __shared__ int deg[W_BKT];
    __shared__ int pre[W_BKT];
    __shared__ int cur[W_BKT];
    __shared__ int stage[STAGE_CAP];
    int b = blockIdx.x;
    int tid = threadIdx.x;
    int beg = bucket_base[b], end = bucket_base[b + 1];
    int n = end - beg;
    if (tid < W_BKT) deg[tid] = 0;
    __syncthreads();
    bool fits = (n <= STAGE_CAP);
    if (fits) {
        for (int i = tid; i < n; i += 256) {
            int val = ebuf2[beg + i].x;
            stage[i] = val;
            atomicAdd(&deg[val & 127], 1);
        }
    } else {
        for (int i = tid; i < n; i += 256)
            atomicAdd(&deg[ebuf2[beg + i].x & 127], 1);
    }
    __syncthreads();
    if (tid < W_BKT) pre[tid] = deg[tid];
    __syncthreads();
    for (int off = 1; off < W_BKT; off <<= 1) {
        int v = (tid >= off && tid < W_BKT) ? pre[tid - off] : 0;
        __syncthreads();
        if (tid < W_BKT) pre[tid] += v;
        __syncthreads();
    }
    if (tid < W_BKT) {
        int v = b * W_BKT + tid;
        int rp = beg + pre[tid] - deg[tid];      // exclusive prefix
        if (v < NN) {
            row_ptr[v] = rp;
            dis[v] = rsqrtf((float)(1 + deg[tid]));
        }
        cur[tid] = rp;
    }
    if (b == NB_BKT - 1 && tid == 0) row_ptr[NN] = NE;
    __syncthreads();
    if (fits) {
        for (int i = tid; i < n; i += 256) {
            int val = stage[i];
            int pos = atomicAdd(&cur[val & 127], 1);
            csr_src[pos] = val >> 7;
        }
    } else {
        for (int i = tid; i < n; i += 256) {
            int val = ebuf2[beg + i].x;
            int pos = atomicAdd(&cur[val & 127], 1);
            csr_src[pos] = val >> 7;
        }
    }
}

// ---------------- dense transforms via MFMA (dis folded into stored rows) ----------------
// W pre-packed into fragment-ordered f16 hi/lo tables. GEMM1: Ah*Bh+Al*Bh+Ah*Bl
// (fp32-equivalent). GEMM2 input h is fp16 (exact) -> Ah*Bh+Ah*Bl only.

__global__ __launch_bounds__(256) void k_wprep(const float* __restrict__ W1,
                                               const float* __restrict__ Wmu,
                                               const float* __restrict__ Wls,
                                               _Float16* __restrict__ wf1h,
                                               _Float16* __restrict__ wf1l,
                                               _Float16* __restrict__ wf2h,
                                               _Float16* __restrict__ wf2l) {
    int tid = threadIdx.x;
    for (int f = tid; f < 4 * 4 * 64; f += 256) {
        int lane = f & 63;
        int kc = (f >> 6) & 3;
        int ct = f >> 8;
        int col = ct * 16 + (lane & 15);
        int k0 = kc * 32 + (lane >> 4) * 8;
#pragma unroll
        for (int j = 0; j < 8; ++j) {
            float w = W1[(k0 + j) * 64 + col];
            _Float16 hi = (_Float16)w;
            wf1h[f * 8 + j] = hi;
            wf1l[f * 8 + j] = (_Float16)(w - (float)hi);
        }
    }
    for (int f = tid; f < 4 * 2 * 64; f += 256) {
        int lane = f & 63;
        int kc = (f >> 6) & 1;
        int ct = f >> 7;
        int col = ct * 16 + (lane & 15);
        int k0 = kc * 32 + (lane >> 4) * 8;
#pragma unroll
        for (int j = 0; j < 8; ++j) {
            int k = k0 + j;
            float w = (col < 32) ? Wmu[k * 32 + col] : Wls[k * 32 + (col - 32)];
            _Float16 hi = (_Float16)w;
            wf2h[f * 8 + j] = hi;
            wf2l[f * 8 + j] = (_Float16)(w - (float)hi);
        }
    }
}

__device__ __forceinline__ void split8(const float4 a, const float4 b,
                                       half8v& hi, half8v& lo) {
    float v[8] = {a.x, a.y, a.z, a.w, b.x, b.y, b.z, b.w};
#pragma unroll
    for (int i = 0; i < 8; ++i) {
        _Float16 h = (_Float16)v[i];
        hi[i] = h;
        lo[i] = (_Float16)(v[i] - (float)h);
    }
}

// t1'[v] = dis[v] * (x[v] @ W1), stored fp16. 64 rows/block, 16 rows/wave, no LDS.
__global__ __launch_bounds__(256) void k_gemm1(const float* __restrict__ x,
                                               const _Float16* __restrict__ wf1h,
                                               const _Float16* __restrict__ wf1l,
                                               const float* __restrict__ dis,
                                               _Float16* __restrict__ t1) {
    int tid = threadIdx.x;
    int lane = tid & 63;
    int wv = tid >> 6;
    int wrow = blockIdx.x * 64 + wv * 16;
    int cl = lane & 15, kg = lane >> 4;
    const half8v* Bh = (const half8v*)wf1h;
    const half8v* Bl = (const half8v*)wf1l;
    float4v acc[4] = {};
    int r = wrow + cl;
    long rr = (r < NN) ? r : (NN - 1);
    const float4* xp = (const float4*)(x + rr * 128);
#pragma unroll
    for (int kc = 0; kc < 4; ++kc) {
        float4 xa = xp[kc * 8 + kg * 2];
        float4 xb = xp[kc * 8 + kg * 2 + 1];
        half8v ah, al;
        split8(xa, xb, ah, al);
#pragma unroll
        for (int ct = 0; ct < 4; ++ct) {
            half8v bh = Bh[(ct * 4 + kc) * 64 + lane];
            half8v bl = Bl[(ct * 4 + kc) * 64 + lane];
            acc[ct] = __builtin_amdgcn_mfma_f32_16x16x32_f16(ah, bh, acc[ct], 0, 0, 0);
            acc[ct] = __builtin_amdgcn_mfma_f32_16x16x32_f16(al, bh, acc[ct], 0, 0, 0);
            acc[ct] = __builtin_amdgcn_mfma_f32_16x16x32_f16(ah, bl, acc[ct], 0, 0, 0);
        }
    }
#pragma unroll
    for (int j = 0; j < 4; ++j) {
        int row = wrow + kg * 4 + j;
        if (row < NN) {
            float dv = dis[row];
#pragma unroll
            for (int ct = 0; ct < 4; ++ct)
                t1[(long)row * 64 + ct * 16 + cl] = (_Float16)(acc[ct][j] * dv);
        }
    }
}

// t2'[v] = dis[v] * (h[v] @ [Wmu | Wls]), h fp16 input, stored fp16
__global__ __launch_bounds__(256) void k_gemm2(const _Float16* __restrict__ h,
                                               const _Float16* __restrict__ wf2h,
                                               const _Float16* __restrict__ wf2l,
                                               const float* __restrict__ dis,
                                               _Float16* __restrict__ t2) {
    int tid = threadIdx.x;
    int lane = tid & 63;
    int wv = tid >> 6;
    int wrow = blockIdx.x * 64 + wv * 16;
    int cl = lane & 15, kg = lane >> 4;
    const half8v* Bh = (const half8v*)wf2h;
    const half8v* Bl = (const half8v*)wf2l;
    float4v acc[4] = {};
    int r = wrow + cl;
    long rr = (r < NN) ? r : (NN - 1);
    const half8v* hp = (const half8v*)(h + rr * 64);
#pragma unroll
    for (int kc = 0; kc < 2; ++kc) {
        half8v ah = hp[kc * 4 + kg];
#pragma unroll
        for (int ct = 0; ct < 4; ++ct) {
            half8v bh = Bh[(ct * 2 + kc) * 64 + lane];
            half8v bl = Bl[(ct * 2 + kc) * 64 + lane];
            acc[ct] = __builtin_amdgcn_mfma_f32_16x16x32_f16(ah, bh, acc[ct], 0, 0, 0);
            acc[ct] = __builtin_amdgcn_mfma_f32_16x16x32_f16(ah, bl, acc[ct], 0, 0, 0);
        }
    }
#pragma unroll
    for (int j = 0; j < 4; ++j) {
        int row = wrow + kg * 4 + j;
        if (row < NN) {
            float dv = dis[row];
#pragma unroll
            for (int ct = 0; ct < 4; ++ct)
                t2[(long)row * 64 + ct * 16 + cl] = (_Float16)(acc[ct][j] * dv);
        }
    }
}

// ---------------- fused gather-aggregations ----------------
// 16 lanes per node, 8 B (half4) per lane -> one wave-instruction gathers 4 full
// 128-B rows. 16-deep load batches; masked tail with clamped duplicate loads.
// ds_swizzle BitMode (literal pattern): lane' = (lane & 0x10) | K.

#define SWZ_LD(K) r[K] = t4[(__builtin_amdgcn_ds_swizzle(idx, ((K) << 5) | 0x10) << 4) + j4];

__device__ __forceinline__ void batch16_full(const half4v* __restrict__ t4, int idx,
                                             int j4, float* a) {
    half4v r[16];
    SWZ_LD(0)  SWZ_LD(1)  SWZ_LD(2)  SWZ_LD(3)
    SWZ_LD(4)  SWZ_LD(5)  SWZ_LD(6)  SWZ_LD(7)
    SWZ_LD(8)  SWZ_LD(9)  SWZ_LD(10) SWZ_LD(11)
    SWZ_LD(12) SWZ_LD(13) SWZ_LD(14) SWZ_LD(15)
#pragma unroll
    for (int k = 0; k < 16; ++k) {
        a[0] += (float)r[k][0]; a[1] += (float)r[k][1];
        a[2] += (float)r[k][2]; a[3] += (float)r[k][3];
    }
}

__device__ __forceinline__ void batch16_mask(const half4v* __restrict__ t4, int idx,
                                             int j4, int cnt, float* a) {
    half4v r[16];
    SWZ_LD(0)  SWZ_LD(1)  SWZ_LD(2)  SWZ_LD(3)
    SWZ_LD(4)  SWZ_LD(5)  SWZ_LD(6)  SWZ_LD(7)
    SWZ_LD(8)  SWZ_LD(9)  SWZ_LD(10) SWZ_LD(11)
    SWZ_LD(12) SWZ_LD(13) SWZ_LD(14) SWZ_LD(15)
#pragma unroll
    for (int k = 0; k < 16; ++k) {
        float w = (k < cnt) ? 1.0f : 0.0f;
        a[0] += w * (float)r[k][0]; a[1] += w * (float)r[k][1];
        a[2] += w * (float)r[k][2]; a[3] += w * (float)r[k][3];
    }
}

__device__ __forceinline__ void batch8_mask(const half4v* __restrict__ t4, int idx,
                                            int j4, int cnt, float* a) {
    half4v r[8];
    SWZ_LD(0)  SWZ_LD(1)  SWZ_LD(2)  SWZ_LD(3)
    SWZ_LD(4)  SWZ_LD(5)  SWZ_LD(6)  SWZ_LD(7)
#pragma unroll
    for (int k = 0; k < 8; ++k) {
        float w = (k < cnt) ? 1.0f : 0.0f;
        a[0] += w * (float)r[k][0]; a[1] += w * (float)r[k][1];
        a[2] += w * (float)r[k][2]; a[3] += w * (float)r[k][3];
    }
}

// h[v] = l2normalize(relu(dis[v]*(sum_s t1'[s] + t1'[v]) + b1)), stored fp16
__global__ __launch_bounds__(256) void k_agg1(const half4v* __restrict__ tv4,
                                              const int* __restrict__ row_ptr,
                                              const int* __restrict__ csr_src,
                                              const float* __restrict__ dis,
                                              const float* __restrict__ b1,
                                              _Float16* __restrict__ h) {
    int lane = threadIdx.x & 63;
    int j4 = lane & 15;
    int v = blockIdx.x * 16 + (threadIdx.x >> 6) * 4 + (lane >> 4);  // NN = 6250*16
    int beg = row_ptr[v], end = row_ptr[v + 1];
    float a[4] = {0.f, 0.f, 0.f, 0.f};
    int base = beg;
    for (; base + 16 <= end; base += 16) {
        int idx = csr_src[base + j4];
        batch16_full(tv4, idx, j4, a);
    }
    int cnt = end - base;
    if (cnt > 0) {
        int idx = csr_src[base + ((j4 < cnt) ? j4 : cnt - 1)];
        if (cnt > 8) batch16_mask(tv4, idx, j4, cnt, a);
        else         batch8_mask(tv4, idx, j4, cnt, a);
    }
    float dv = dis[v];
    half4v rv = tv4[(v << 4) + j4];              // = dis[v]*t1[v]
    float4 bb = ((const float4*)b1)[j4];
    float val0 = fmaxf(dv * (a[0] + (float)rv[0]) + bb.x, 0.0f);
    float val1 = fmaxf(dv * (a[1] + (float)rv[1]) + bb.y, 0.0f);
    float val2 = fmaxf(dv * (a[2] + (float)rv[2]) + bb.z, 0.0f);
    float val3 = fmaxf(dv * (a[3] + (float)rv[3]) + bb.w, 0.0f);
    float ss = val0 * val0 + val1 * val1 + val2 * val2 + val3 * val3;
#pragma unroll
    for (int m = 1; m < 16; m <<= 1) ss += __shfl_xor(ss, m);
    float scale = 1.0f / fmaxf(sqrtf(ss), 1e-12f);
    half4v* h4 = (half4v*)h;
    half4v hv;
    hv[0] = (_Float16)(val0 * scale); hv[1] = (_Float16)(val1 * scale);
    hv[2] = (_Float16)(val2 * scale); hv[3] = (_Float16)(val3 * scale);
    h4[(v << 4) + j4] = hv;
}

// layer-2 aggregation fused with bias + reparametrize; writes mu, ls (f32), z (fp16)
__global__ __launch_bounds__(256) void k_agg2(const half4v* __restrict__ tv4,
                                              const int* __restrict__ row_ptr,
                                              const int* __restrict__ csr_src,
                                              const float* __restrict__ dis,
                                              const float* __restrict__ bmu,
                                              const float* __restrict__ bls,
                                              const float* __restrict__ eps,
                                              float* __restrict__ mu,
                                              float* __restrict__ ls,
                                              _Float16* __restrict__ zh) {
    int lane = threadIdx.x & 63;
    int j4 = lane & 15;
    int v = blockIdx.x * 16 + (threadIdx.x >> 6) * 4 + (lane >> 4);
    int beg = row_ptr[v], end = row_ptr[v + 1];
    float a[4] = {0.f, 0.f, 0.f, 0.f};
    int base = beg;
    for (; base + 16 <= end; base += 16) {
        int idx = csr_src[base + j4];
        batch16_full(tv4, idx, j4, a);
    }
    int cnt = end - base;
    if (cnt > 0) {
        int idx = csr_src[base + ((j4 < cnt) ? j4 : cnt - 1)];
        if (cnt > 8) batch16_mask(tv4, idx, j4, cnt, a);
        else         batch8_mask(tv4, idx, j4, cnt, a);
    }
    float dv = dis[v];
    half4v rv = tv4[(v << 4) + j4];              // = dis[v]*t2[v]
    float4 bb = (j4 < 8) ? ((const float4*)bmu)[j4] : ((const float4*)bls)[j4 - 8];
    float val0 = dv * (a[0] + (float)rv[0]) + bb.x;
    float val1 = dv * (a[1] + (float)rv[1]) + bb.y;
    float val2 = dv * (a[2] + (float)rv[2]) + bb.z;
    float val3 = dv * (a[3] + (float)rv[3]) + bb.w;
    // partner lane (j4^8) holds the logstd (resp. mu) for the same dims
    float o0 = __shfl_xor(val0, 8);
    float o1 = __shfl_xor(val1, 8);
    float o2 = __shfl_xor(val2, 8);
    float o3 = __shfl_xor(val3, 8);
    float4v* mu4 = (float4v*)mu;
    float4v* ls4 = (float4v*)ls;
    half4v* z4  = (half4v*)zh;
    const float4* e4 = (const float4*)eps;
    if (j4 < 8) {
        float4v mv; mv.x = val0; mv.y = val1; mv.z = val2; mv.w = val3;
        __builtin_nontemporal_store(mv, &mu4[(v << 3) + j4]);
        float4 ev = e4[(v << 3) + j4];
        float l0 = fminf(fmaxf(o0, -10.0f), 10.0f);
        float l1 = fminf(fmaxf(o1, -10.0f), 10.0f);
        float l2 = fminf(fmaxf(o2, -10.0f), 10.0f);
        float l3 = fminf(fmaxf(o3, -10.0f), 10.0f);
        half4v zw;
        zw[0] = (_Float16)(val0 + ev.x * expf(l0));
        zw[1] = (_Float16)(val1 + ev.y * expf(l1));
        zw[2] = (_Float16)(val2 + ev.z * expf(l2));
        zw[3] = (_Float16)(val3 + ev.w * expf(l3));
        z4[(v << 3) + j4] = zw;
    } else {
        float4v lv; lv.x = val0; lv.y = val1; lv.z = val2; lv.w = val3;
        __builtin_nontemporal_store(lv, &ls4[(v << 3) + (j4 - 8)]);
    }
}

// ---------------- bucket-ordered decode (no LDS, MLP-restored) ----------------
// 4 blocks per bucket; dst rows live in an 8-KB window -> L1/L2 hits from global.
// 4 lanes/edge, half8 (16-B) loads, 4-edge batch per group. int2 ebuf2 gives
// (val, edge-id) in one 8-B load. Clamped-duplicate tail with masked store.
__global__ __launch_bounds__(256) void k_decode(const _Float16* __restrict__ zh,
                                                const int* __restrict__ bucket_base,
                                                const int2* __restrict__ ebuf2,
                                                float* __restrict__ out) {
    int blk = blockIdx.x;
    int b = blk >> 2, part = blk & 3;
    int beg0 = bucket_base[b], end0 = bucket_base[b + 1];
    int n = end0 - beg0;
    int qsz = (n + 3) >> 2;
    int beg = beg0 + part * qsz;
    int end = beg + qsz; if (end > end0) end = end0;
    long zb = (long)b * W_BKT * 4;                 // dst-row base (half8 units)
    int j = threadIdx.x & 3;                       // dim slice [8j, 8j+8)
    int gi = threadIdx.x >> 2;                     // group id in block [0,64)
    const half8v* z8 = (const half8v*)zh;
    for (int p0 = beg + gi * 4; p0 < end; p0 += 256) {
        int cnt = end - p0; if (cnt > 4) cnt = 4;
        int2 w[4];
#pragma unroll
        for (int k = 0; k < 4; ++k) w[k] = ebuf2[p0 + ((k < cnt) ? k : cnt - 1)];
        half8v za[4], zd[4];
#pragma unroll
        for (int k = 0; k < 4; ++k) {
            za[k] = z8[(long)(w[k].x >> 7) * 4 + j];        // random 64-B row (src)
            zd[k] = z8[zb + (long)(w[k].x & 127) * 4 + j];  // hot 8-KB window (dst)
        }
#pragma unroll
        for (int k = 0; k < 4; ++k) {
            float d = 0.f;
#pragma unroll
            for (int i = 0; i < 8; ++i) d += (float)za[k][i] * (float)zd[k][i];
            d += __shfl_xor(d, 1);
            d += __shfl_xor(d, 2);
            if (j == 0 && k < cnt)
                out[w[k].y] = 1.0f / (1.0f + expf(-d));
        }
    }
}

extern "C" void kernel_launch(void* const* d_in, const int* in_sizes, int n_in,
                              void* d_out, int out_size, void* d_ws, size_t ws_size,
                              hipStream_t stream) {
    const float* x   = (const float*)d_in[0];
    const int*   ei  = (const int*)d_in[1];
    const float* eps = (const float*)d_in[2];
    const float* W1  = (const float*)d_in[3];
    const float* b1  = (const float*)d_in[4];
    const float* Wmu = (const float*)d_in[5];
    const float* bmu = (const float*)d_in[6];
    const float* Wls = (const float*)d_in[7];
    const float* bls = (const float*)d_in[8];
    const int* src = ei;        // edge_index[0]
    const int* dst = ei + NE;   // edge_index[1]

    float* out = (float*)d_out;
    float* adj = out;                       // [E]
    float* mu  = out + NE;                  // [N,32]
    float* ls  = mu + (long)NN * 32;        // [N,32]

    // workspace layout (all block byte sizes multiples of 16; zh 64B-aligned)
    float* dis      = (float*)d_ws;              // NN
    int*   row_ptr  = (int*)(dis + NN);          // 100004
    int*   bucket_base = row_ptr + 100004;       // NB_BKT+1 -> pad 784
    int*   counts   = bucket_base + 784;         // NT*NB_BKT = 76636 -> pad 76640
    int2*  ebuf2    = (int2*)(counts + 76640);   // NE int2 (val, eid) — 8B-aligned
    int*   csr_src  = (int*)(ebuf2 + NE);        // NE
    _Float16* t     = (_Float16*)(csr_src + NE); // NN*64 fp16 (t1' then t2')
    _Float16* h     = t + (long)NN * 64;         // NN*64 fp16
    _Float16* zh    = h + (long)NN * 64 + 24;    // NN*32 fp16, 64B-aligned

    // W fragment tables alias the counts region (dead after k_place; k_wprep is
    // stream-ordered after k_place). 49152 B << 306 KB region, 16B-aligned.
    _Float16* wf1h = (_Float16*)counts;          // 16x64x8 = 8192 f16
    _Float16* wf1l = wf1h + 8192;                // 8192
    _Float16* wf2h = wf1l + 8192;                // 8x64x8 = 4096
    _Float16* wf2l = wf2h + 4096;                // 4096

    const int B = 256;

    // CSR + deg/dis build — zero global atomics
    k_cnt  <<<NT, B, 0, stream>>>(dst, counts);
    k_bscan<<<1, 1024, 0, stream>>>(counts, bucket_base);   // scan + tile offsets
    k_place<<<NT, 1024, 0, stream>>>(src, dst, counts, ebuf2);
    k_wprep<<<1, B, 0, stream>>>(W1, Wmu, Wls, wf1h, wf1l, wf2h, wf2l);
    k_build<<<NB_BKT, B, 0, stream>>>(bucket_base, ebuf2, csr_src, row_ptr, dis);

    // layer 1
    k_gemm1<<<(NN + 63) / 64, B, 0, stream>>>(x, wf1h, wf1l, dis, t);
    k_agg1 <<<NN / 16, B, 0, stream>>>((const half4v*)t, row_ptr, csr_src, dis, b1, h);

    // layer 2
    k_gemm2<<<(NN + 63) / 64, B, 0, stream>>>(h, wf2h, wf2l, dis, t);
    k_agg2 <<<NN / 16, B, 0, stream>>>((const half4v*)t, row_ptr, csr_src, dis,
                                       bmu, bls, eps, mu, ls, zh);

    // decode (bucket order, 4 blocks/bucket, dst rows via cache, scatter via ebuf2.y)
    k_decode<<<NB_BKT * 4, B, 0, stream>>>(zh, bucket_base, ebuf2, adj);
}

// Round 11
// 350.366 us; speedup vs baseline: 1.2541x; 1.0669x over previous
//
#include <hip/hip_runtime.h>
#include <hip/hip_fp16.h>

#define NN 100000
#define NE 1600000
#define W_BKT 128
#define NB_BKT ((NN + W_BKT - 1) / W_BKT)   // 782
#define TILE_E 16384                         // edges per counting-sort tile
#define NT ((NE + TILE_E - 1) / TILE_E)      // 98
#define STAGE_CAP 4352                       // LDS staging (avg bucket ~2048)
// IN=128, HID=64, OUT=32

typedef _Float16 half2v __attribute__((ext_vector_type(2)));
typedef _Float16 half4v __attribute__((ext_vector_type(4)));
typedef _Float16 half8v __attribute__((ext_vector_type(8)));
typedef float float2v __attribute__((ext_vector_type(2)));
typedef float float4v __attribute__((ext_vector_type(4)));

// ---- deterministic two-pass bucket sort + fused CSR/deg build (NO global atomics) ----

__global__ __launch_bounds__(256) void k_cnt(const int* __restrict__ dst,
                                             int* __restrict__ counts) {
    __shared__ int hc[NB_BKT];
    int tid = threadIdx.x;
    for (int i = tid; i < NB_BKT; i += 256) hc[i] = 0;
    __syncthreads();
    int base = blockIdx.x * TILE_E;
    int lim = base + TILE_E; if (lim > NE) lim = NE;
    for (int e = base + tid; e < lim; e += 256)
        atomicAdd(&hc[dst[e] >> 7], 1);
    __syncthreads();
    for (int i = tid; i < NB_BKT; i += 256)
        counts[blockIdx.x * NB_BKT + i] = hc[i];
}

__global__ __launch_bounds__(1024) void k_bscan(const int* __restrict__ counts,
                                                int* __restrict__ bucket_base) {
    __shared__ int buf[1024];
    int tid = threadIdx.x;
    int total = 0;
    if (tid < NB_BKT)
        for (int t = 0; t < NT; ++t) total += counts[t * NB_BKT + tid];
    buf[tid] = total;
    __syncthreads();
    for (int off = 1; off < 1024; off <<= 1) {
        int v = (tid >= off) ? buf[tid - off] : 0;
        __syncthreads();
        buf[tid] += v;
        __syncthreads();
    }
    if (tid < NB_BKT) bucket_base[tid] = buf[tid] - total;   // exclusive
    if (tid == 0) bucket_base[NB_BKT] = NE;
}

__global__ __launch_bounds__(256) void k_offs(const int* __restrict__ bucket_base,
                                              int* __restrict__ counts) {
    int b = blockIdx.x * 256 + threadIdx.x;
    if (b >= NB_BKT) return;
    int off = bucket_base[b];
    for (int t = 0; t < NT; ++t) {
        int c = counts[t * NB_BKT + b];
        counts[t * NB_BKT + b] = off;
        off += c;
    }
}

__global__ __launch_bounds__(256) void k_place(const int* __restrict__ src,
                                               const int* __restrict__ dst,
                                               const int* __restrict__ counts,
                                               int* __restrict__ ebuf) {
    __shared__ int cur[NB_BKT];
    int tid = threadIdx.x;
    for (int i = tid; i < NB_BKT; i += 256)
        cur[i] = counts[blockIdx.x * NB_BKT + i];
    __syncthreads();
    int base = blockIdx.x * TILE_E;
    int lim = base + TILE_E; if (lim > NE) lim = NE;
    for (int e = base + tid; e < lim; e += 256) {
        int s = src[e], d = dst[e];
        int pos = atomicAdd(&cur[d >> 7], 1);     // LDS atomic, ~21/counter
        ebuf[pos] = (s << 7) | (d & 127);
    }
}

// one block per bucket: LDS-stage the bucket's ebuf slice, count 128 node degs,
// prefix-scan -> row_ptr + dis, then scatter to csr_src.
__global__ __launch_bounds__(256) void k_build(const int* __restrict__ bucket_base,
                                               const int* __restrict__ ebuf,
                                               int* __restrict__ csr_src,
                                               int* __restrict__ row_ptr,
                                               float* __restrict__ dis) {
    __shared__ int deg[W_BKT];
    __shared__ int pre[W_BKT];
    __shared__ int cur[W_BKT];
    __shared__ int stage[STAGE_CAP];
    int b = blockIdx.x;
    int tid = threadIdx.x;
    int beg = bucket_base[b], end = bucket_base[b + 1];
    int n = end - beg;
    if (tid < W_BKT) deg[tid] = 0;
    __syncthreads();
    bool fits = (n <= STAGE_CAP);
    if (fits) {
        for (int i = tid; i < n; i += 256) {
            int val = ebuf[beg + i];
            stage[i] = val;
            atomicAdd(&deg[val & 127], 1);
        }
    } else {
        for (int i = tid; i < n; i += 256)
            atomicAdd(&deg[ebuf[beg + i] & 127], 1);
    }
    __syncthreads();
    if (tid < W_BKT) pre[tid] = deg[tid];
    __syncthreads();
    for (int off = 1; off < W_BKT; off <<= 1) {
        int v = (tid >= off && tid < W_BKT) ? pre[tid - off] : 0;
        __syncthreads();
        if (tid < W_BKT) pre[tid] += v;
        __syncthreads();
    }
    if (tid < W_BKT) {
        int v = b * W_BKT + tid;
        int rp = beg + pre[tid] - deg[tid];      // exclusive prefix
        if (v < NN) {
            row_ptr[v] = rp;
            dis[v] = rsqrtf((float)(1 + deg[tid]));
        }
        cur[tid] = rp;
    }
    if (b == NB_BKT - 1 && tid == 0) row_ptr[NN] = NE;
    __syncthreads();
    if (fits) {
        for (int i = tid; i < n; i += 256) {
            int val = stage[i];
            int pos = atomicAdd(&cur[val & 127], 1);
            csr_src[pos] = val >> 7;
        }
    } else {
        for (int i = tid; i < n; i += 256) {
            int val = ebuf[beg + i];
            int pos = atomicAdd(&cur[val & 127], 1);
            csr_src[pos] = val >> 7;
        }
    }
}

// ---------------- dense transforms via MFMA (dis folded into stored rows) ----------------
// W pre-packed into fragment-ordered f16 hi/lo tables (split: w = hi + lo, lo captures
// the fp16 rounding residual). GEMM computes Ah*Bh + Al*Bh + Ah*Bl -> fp32-equivalent.

__global__ __launch_bounds__(256) void k_wprep(const float* __restrict__ W1,
                                               const float* __restrict__ Wmu,
                                               const float* __restrict__ Wls,
                                               _Float16* __restrict__ wf1h,
                                               _Float16* __restrict__ wf1l,
                                               _Float16* __restrict__ wf2h,
                                               _Float16* __restrict__ wf2l) {
    int tid = threadIdx.x;
    // gemm1 fragments: frag f = (ct*4 + kc)*64 + lane, 8 consecutive k per lane
    for (int f = tid; f < 4 * 4 * 64; f += 256) {
        int lane = f & 63;
        int kc = (f >> 6) & 3;
        int ct = f >> 8;
        int col = ct * 16 + (lane & 15);
        int k0 = kc * 32 + (lane >> 4) * 8;
#pragma unroll
        for (int j = 0; j < 8; ++j) {
            float w = W1[(k0 + j) * 64 + col];
            _Float16 hi = (_Float16)w;
            wf1h[f * 8 + j] = hi;
            wf1l[f * 8 + j] = (_Float16)(w - (float)hi);
        }
    }
    // gemm2 fragments: frag f = (ct*2 + kc)*64 + lane; cols = [Wmu | Wls]
    for (int f = tid; f < 4 * 2 * 64; f += 256) {
        int lane = f & 63;
        int kc = (f >> 6) & 1;
        int ct = f >> 7;
        int col = ct * 16 + (lane & 15);
        int k0 = kc * 32 + (lane >> 4) * 8;
#pragma unroll
        for (int j = 0; j < 8; ++j) {
            int k = k0 + j;
            float w = (col < 32) ? Wmu[k * 32 + col] : Wls[k * 32 + (col - 32)];
            _Float16 hi = (_Float16)w;
            wf2h[f * 8 + j] = hi;
            wf2l[f * 8 + j] = (_Float16)(w - (float)hi);
        }
    }
}

__device__ __forceinline__ void split8(const float4 a, const float4 b,
                                       half8v& hi, half8v& lo) {
    float v[8] = {a.x, a.y, a.z, a.w, b.x, b.y, b.z, b.w};
#pragma unroll
    for (int i = 0; i < 8; ++i) {
        _Float16 h = (_Float16)v[i];
        hi[i] = h;
        lo[i] = (_Float16)(v[i] - (float)h);
    }
}

// t1'[v] = dis[v] * (x[v] @ W1), stored fp16. 64 rows/block, 16 rows/wave, no LDS.
__global__ __launch_bounds__(256) void k_gemm1(const float* __restrict__ x,
                                               const _Float16* __restrict__ wf1h,
                                               const _Float16* __restrict__ wf1l,
                                               const float* __restrict__ dis,
                                               _Float16* __restrict__ t1) {
    int tid = threadIdx.x;
    int lane = tid & 63;
    int wv = tid >> 6;
    int wrow = blockIdx.x * 64 + wv * 16;
    int cl = lane & 15, kg = lane >> 4;
    const half8v* Bh = (const half8v*)wf1h;
    const half8v* Bl = (const half8v*)wf1l;
    float4v acc[4] = {};
    int r = wrow + cl;
    long rr = (r < NN) ? r : (NN - 1);
    const float4* xp = (const float4*)(x + rr * 128);
#pragma unroll
    for (int kc = 0; kc < 4; ++kc) {
        float4 xa = xp[kc * 8 + kg * 2];
        float4 xb = xp[kc * 8 + kg * 2 + 1];
        half8v ah, al;
        split8(xa, xb, ah, al);
#pragma unroll
        for (int ct = 0; ct < 4; ++ct) {
            half8v bh = Bh[(ct * 4 + kc) * 64 + lane];
            half8v bl = Bl[(ct * 4 + kc) * 64 + lane];
            acc[ct] = __builtin_amdgcn_mfma_f32_16x16x32_f16(ah, bh, acc[ct], 0, 0, 0);
            acc[ct] = __builtin_amdgcn_mfma_f32_16x16x32_f16(al, bh, acc[ct], 0, 0, 0);
            acc[ct] = __builtin_amdgcn_mfma_f32_16x16x32_f16(ah, bl, acc[ct], 0, 0, 0);
        }
    }
#pragma unroll
    for (int j = 0; j < 4; ++j) {
        int row = wrow + kg * 4 + j;
        if (row < NN) {
            float dv = dis[row];
#pragma unroll
            for (int ct = 0; ct < 4; ++ct)
                t1[(long)row * 64 + ct * 16 + cl] = (_Float16)(acc[ct][j] * dv);
        }
    }
}

// t2'[v] = dis[v] * (h[v] @ [Wmu | Wls]), stored fp16
__global__ __launch_bounds__(256) void k_gemm2(const float* __restrict__ h,
                                               const _Float16* __restrict__ wf2h,
                                               const _Float16* __restrict__ wf2l,
                                               const float* __restrict__ dis,
                                               _Float16* __restrict__ t2) {
    int tid = threadIdx.x;
    int lane = tid & 63;
    int wv = tid >> 6;
    int wrow = blockIdx.x * 64 + wv * 16;
    int cl = lane & 15, kg = lane >> 4;
    const half8v* Bh = (const half8v*)wf2h;
    const half8v* Bl = (const half8v*)wf2l;
    float4v acc[4] = {};
    int r = wrow + cl;
    long rr = (r < NN) ? r : (NN - 1);
    const float4* hp = (const float4*)(h + rr * 64);
#pragma unroll
    for (int kc = 0; kc < 2; ++kc) {
        float4 xa = hp[kc * 8 + kg * 2];
        float4 xb = hp[kc * 8 + kg * 2 + 1];
        half8v ah, al;
        split8(xa, xb, ah, al);
#pragma unroll
        for (int ct = 0; ct < 4; ++ct) {
            half8v bh = Bh[(ct * 2 + kc) * 64 + lane];
            half8v bl = Bl[(ct * 2 + kc) * 64 + lane];
            acc[ct] = __builtin_amdgcn_mfma_f32_16x16x32_f16(ah, bh, acc[ct], 0, 0, 0);
            acc[ct] = __builtin_amdgcn_mfma_f32_16x16x32_f16(al, bh, acc[ct], 0, 0, 0);
            acc[ct] = __builtin_amdgcn_mfma_f32_16x16x32_f16(ah, bl, acc[ct], 0, 0, 0);
        }
    }
#pragma unroll
    for (int j = 0; j < 4; ++j) {
        int row = wrow + kg * 4 + j;
        if (row < NN) {
            float dv = dis[row];
#pragma unroll
            for (int ct = 0; ct < 4; ++ct)
                t2[(long)row * 64 + ct * 16 + cl] = (_Float16)(acc[ct][j] * dv);
        }
    }
}

// ---------------- fused gather-aggregations ----------------
// 16 lanes per node, 8 B (half4) per lane -> one wave-instruction gathers 4 full
// 128-B rows (= 4 L2 lines, no over-fetch). 16-deep load batches; masked tail batch
// with clamped duplicate-address loads (L1 hits, no serial tail).
// ds_swizzle BitMode (literal pattern): lane' = (lane & 0x10) | K.

#define SWZ_LD(K) r[K] = t4[(__builtin_amdgcn_ds_swizzle(idx, ((K) << 5) | 0x10) << 4) + j4];

__device__ __forceinline__ void batch16_full(const half4v* __restrict__ t4, int idx,
                                             int j4, float* a) {
    half4v r[16];
    SWZ_LD(0)  SWZ_LD(1)  SWZ_LD(2)  SWZ_LD(3)
    SWZ_LD(4)  SWZ_LD(5)  SWZ_LD(6)  SWZ_LD(7)
    SWZ_LD(8)  SWZ_LD(9)  SWZ_LD(10) SWZ_LD(11)
    SWZ_LD(12) SWZ_LD(13) SWZ_LD(14) SWZ_LD(15)
#pragma unroll
    for (int k = 0; k < 16; ++k) {
        a[0] += (float)r[k][0]; a[1] += (float)r[k][1];
        a[2] += (float)r[k][2]; a[3] += (float)r[k][3];
    }
}

__device__ __forceinline__ void batch16_mask(const half4v* __restrict__ t4, int idx,
                                             int j4, int cnt, float* a) {
    half4v r[16];
    SWZ_LD(0)  SWZ_LD(1)  SWZ_LD(2)  SWZ_LD(3)
    SWZ_LD(4)  SWZ_LD(5)  SWZ_LD(6)  SWZ_LD(7)
    SWZ_LD(8)  SWZ_LD(9)  SWZ_LD(10) SWZ_LD(11)
    SWZ_LD(12) SWZ_LD(13) SWZ_LD(14) SWZ_LD(15)
#pragma unroll
    for (int k = 0; k < 16; ++k) {
        float w = (k < cnt) ? 1.0f : 0.0f;
        a[0] += w * (float)r[k][0]; a[1] += w * (float)r[k][1];
        a[2] += w * (float)r[k][2]; a[3] += w * (float)r[k][3];
    }
}

__device__ __forceinline__ void batch8_mask(const half4v* __restrict__ t4, int idx,
                                            int j4, int cnt, float* a) {
    half4v r[8];
    SWZ_LD(0)  SWZ_LD(1)  SWZ_LD(2)  SWZ_LD(3)
    SWZ_LD(4)  SWZ_LD(5)  SWZ_LD(6)  SWZ_LD(7)
#pragma unroll
    for (int k = 0; k < 8; ++k) {
        float w = (k < cnt) ? 1.0f : 0.0f;
        a[0] += w * (float)r[k][0]; a[1] += w * (float)r[k][1];
        a[2] += w * (float)r[k][2]; a[3] += w * (float)r[k][3];
    }
}

// h[v] = l2normalize(relu(dis[v]*(sum_s t1'[s] + t1'[v]) + b1))
__global__ __launch_bounds__(256) void k_agg1(const half4v* __restrict__ tv4,
                                              const int* __restrict__ row_ptr,
                                              const int* __restrict__ csr_src,
                                              const float* __restrict__ dis,
                                              const float* __restrict__ b1,
                                              float* __restrict__ h) {
    int lane = threadIdx.x & 63;
    int j4 = lane & 15;
    int v = blockIdx.x * 16 + (threadIdx.x >> 6) * 4 + (lane >> 4);  // NN = 6250*16
    int beg = row_ptr[v], end = row_ptr[v + 1];
    float a[4] = {0.f, 0.f, 0.f, 0.f};
    int base = beg;
    for (; base + 16 <= end; base += 16) {
        int idx = csr_src[base + j4];
        batch16_full(tv4, idx, j4, a);
    }
    int cnt = end - base;
    if (cnt > 0) {
        int idx = csr_src[base + ((j4 < cnt) ? j4 : cnt - 1)];
        if (cnt > 8) batch16_mask(tv4, idx, j4, cnt, a);
        else         batch8_mask(tv4, idx, j4, cnt, a);
    }
    float dv = dis[v];
    half4v rv = tv4[(v << 4) + j4];              // = dis[v]*t1[v]
    float4 bb = ((const float4*)b1)[j4];
    float val0 = fmaxf(dv * (a[0] + (float)rv[0]) + bb.x, 0.0f);
    float val1 = fmaxf(dv * (a[1] + (float)rv[1]) + bb.y, 0.0f);
    float val2 = fmaxf(dv * (a[2] + (float)rv[2]) + bb.z, 0.0f);
    float val3 = fmaxf(dv * (a[3] + (float)rv[3]) + bb.w, 0.0f);
    float ss = val0 * val0 + val1 * val1 + val2 * val2 + val3 * val3;
#pragma unroll
    for (int m = 1; m < 16; m <<= 1) ss += __shfl_xor(ss, m);
    float scale = 1.0f / fmaxf(sqrtf(ss), 1e-12f);
    float4v* h4 = (float4v*)h;
    float4v hv; hv.x = val0 * scale; hv.y = val1 * scale;
    hv.z = val2 * scale; hv.w = val3 * scale;
    h4[(v << 4) + j4] = hv;
}

// layer-2 aggregation fused with bias + reparametrize; writes mu, ls (f32), z (fp16)
__global__ __launch_bounds__(256) void k_agg2(const half4v* __restrict__ tv4,
                                              const int* __restrict__ row_ptr,
                                              const int* __restrict__ csr_src,
                                              const float* __restrict__ dis,
                                              const float* __restrict__ bmu,
                                              const float* __restrict__ bls,
                                              const float* __restrict__ eps,
                                              float* __restrict__ mu,
                                              float* __restrict__ ls,
                                              _Float16* __restrict__ zh) {
    int lane = threadIdx.x & 63;
    int j4 = lane & 15;
    int v = blockIdx.x * 16 + (threadIdx.x >> 6) * 4 + (lane >> 4);
    int beg = row_ptr[v], end = row_ptr[v + 1];
    float a[4] = {0.f, 0.f, 0.f, 0.f};
    int base = beg;
    for (; base + 16 <= end; base += 16) {
        int idx = csr_src[base + j4];
        batch16_full(tv4, idx, j4, a);
    }
    int cnt = end - base;
    if (cnt > 0) {
        int idx = csr_src[base + ((j4 < cnt) ? j4 : cnt - 1)];
        if (cnt > 8) batch16_mask(tv4, idx, j4, cnt, a);
        else         batch8_mask(tv4, idx, j4, cnt, a);
    }
    float dv = dis[v];
    half4v rv = tv4[(v << 4) + j4];              // = dis[v]*t2[v]
    float4 bb = (j4 < 8) ? ((const float4*)bmu)[j4] : ((const float4*)bls)[j4 - 8];
    float val0 = dv * (a[0] + (float)rv[0]) + bb.x;
    float val1 = dv * (a[1] + (float)rv[1]) + bb.y;
    float val2 = dv * (a[2] + (float)rv[2]) + bb.z;
    float val3 = dv * (a[3] + (float)rv[3]) + bb.w;
    // partner lane (j4^8) holds the logstd (resp. mu) for the same dims
    float o0 = __shfl_xor(val0, 8);
    float o1 = __shfl_xor(val1, 8);
    float o2 = __shfl_xor(val2, 8);
    float o3 = __shfl_xor(val3, 8);
    float4v* mu4 = (float4v*)mu;
    float4v* ls4 = (float4v*)ls;
    half4v* z4  = (half4v*)zh;
    const float4* e4 = (const float4*)eps;
    if (j4 < 8) {
        float4v mv; mv.x = val0; mv.y = val1; mv.z = val2; mv.w = val3;
        __builtin_nontemporal_store(mv, &mu4[(v << 3) + j4]);
        float4 ev = e4[(v << 3) + j4];
        float l0 = fminf(fmaxf(o0, -10.0f), 10.0f);
        float l1 = fminf(fmaxf(o1, -10.0f), 10.0f);
        float l2 = fminf(fmaxf(o2, -10.0f), 10.0f);
        float l3 = fminf(fmaxf(o3, -10.0f), 10.0f);
        half4v zw;
        zw[0] = (_Float16)(val0 + ev.x * expf(l0));
        zw[1] = (_Float16)(val1 + ev.y * expf(l1));
        zw[2] = (_Float16)(val2 + ev.z * expf(l2));
        zw[3] = (_Float16)(val3 + ev.w * expf(l3));
        z4[(v << 3) + j4] = zw;
    } else {
        float4v lv; lv.x = val0; lv.y = val1; lv.z = val2; lv.w = val3;
        __builtin_nontemporal_store(lv, &ls4[(v << 3) + (j4 - 8)]);
    }
}

// adj_pred[e] = sigmoid(<z[src], z[dst]>); z fp16 (row = 64 B),
// 4 lanes per edge, 16 B loads
__global__ __launch_bounds__(256) void k_decode(const _Float16* __restrict__ zh,
                                                const int* __restrict__ src,
                                                const int* __restrict__ dst,
                                                float* __restrict__ out) {
    long t = (long)blockIdx.x * 256 + threadIdx.x;
    long e = t >> 2; int l = (int)(t & 3);
    if (e >= NE) return;
    int s = src[e], d = dst[e];
    const half8v* z8 = (const half8v*)zh;
    half8v a = z8[s * 4 + l];
    half8v b = z8[d * 4 + l];
    float p = 0.f;
#pragma unroll
    for (int i = 0; i < 8; ++i) p += (float)a[i] * (float)b[i];
    p += __shfl_xor(p, 1);
    p += __shfl_xor(p, 2);
    if (l == 0) out[e] = 1.0f / (1.0f + expf(-p));
}

extern "C" void kernel_launch(void* const* d_in, const int* in_sizes, int n_in,
                              void* d_out, int out_size, void* d_ws, size_t ws_size,
                              hipStream_t stream) {
    const float* x   = (const float*)d_in[0];
    const int*   ei  = (const int*)d_in[1];
    const float* eps = (const float*)d_in[2];
    const float* W1  = (const float*)d_in[3];
    const float* b1  = (const float*)d_in[4];
    const float* Wmu = (const float*)d_in[5];
    const float* bmu = (const float*)d_in[6];
    const float* Wls = (const float*)d_in[7];
    const float* bls = (const float*)d_in[8];
    const int* src = ei;        // edge_index[0]
    const int* dst = ei + NE;   // edge_index[1]

    float* out = (float*)d_out;
    float* adj = out;                       // [E]
    float* mu  = out + NE;                  // [N,32]
    float* ls  = mu + (long)NN * 32;        // [N,32]

    // workspace layout (all block byte sizes multiples of 16; z 64B-aligned)
    float* dis      = (float*)d_ws;              // NN
    int*   row_ptr  = (int*)(dis + NN);          // 100004
    int*   bucket_base = row_ptr + 100004;       // NB_BKT+1 -> pad 784
    int*   counts   = bucket_base + 784;         // NT*NB_BKT = 76636 -> pad 76640
    int*   ebuf     = counts + 76640;            // NE
    int*   csr_src  = ebuf + NE;                 // NE
    _Float16* t     = (_Float16*)(csr_src + NE); // NN*64 fp16 (t1' then t2')
    float* h        = (float*)(t + (long)NN * 64);         // NN*64 f32
    _Float16* zh    = (_Float16*)(h + (long)NN * 64 + 12); // NN*32 fp16, 64B-aligned

    // W fragment tables alias the counts region (dead after k_place; k_wprep is
    // stream-ordered after k_place). 49152 B << 306 KB region, 16B-aligned.
    _Float16* wf1h = (_Float16*)counts;          // 16x64x8 = 8192 f16
    _Float16* wf1l = wf1h + 8192;                // 8192
    _Float16* wf2h = wf1l + 8192;                // 8x64x8 = 4096
    _Float16* wf2l = wf2h + 4096;                // 4096

    const int B = 256;

    // CSR + deg/dis build — zero global atomics
    k_cnt  <<<NT, B, 0, stream>>>(dst, counts);
    k_bscan<<<1, 1024, 0, stream>>>(counts, bucket_base);
    k_offs <<<(NB_BKT + B - 1) / B, B, 0, stream>>>(bucket_base, counts);
    k_place<<<NT, B, 0, stream>>>(src, dst, counts, ebuf);
    k_wprep<<<1, B, 0, stream>>>(W1, Wmu, Wls, wf1h, wf1l, wf2h, wf2l);
    k_build<<<NB_BKT, B, 0, stream>>>(bucket_base, ebuf, csr_src, row_ptr, dis);

    // layer 1
    k_gemm1<<<(NN + 63) / 64, B, 0, stream>>>(x, wf1h, wf1l, dis, t);
    k_agg1 <<<NN / 16, B, 0, stream>>>((const half4v*)t, row_ptr, csr_src, dis, b1, h);

    // layer 2
    k_gemm2<<<(NN + 63) / 64, B, 0, stream>>>(h, wf2h, wf2l, dis, t);
    k_agg2 <<<NN / 16, B, 0, stream>>>((const half4v*)t, row_ptr, csr_src, dis,
                                       bmu, bls, eps, mu, ls, zh);

    // decode
    k_decode<<<(int)(((long)NE * 4 + B - 1) / B), B, 0, stream>>>(zh, src, dst, adj);
}